// Round 15
// baseline (591.775 us; speedup 1.0000x reference)
//
#include <hip/hip_runtime.h>
#include <hip/hip_bf16.h>
#include <stdint.h>

#define L_SEQ 4096
#define H_DIM 768
#define N_HEADS 12
#define D_HEAD 64
#define N_CHUNK 32
#define CHUNK 128
#define FF_DIM 3072
#define OUT_DIM 384
#define BATCH 2
#define EPS_LN 1e-5f
#define M_ROWS (BATCH * L_SEQ)   /* 8192 */
#define QKV_LD (3 * H_DIM)       /* 2304 */
#define NLOC (BATCH * N_HEADS * N_CHUNK)  /* 768 local-attn blocks */
#define NGSEG 8                   /* global-row segments of 512 keys */

typedef unsigned short u16;
typedef __bf16 bx8 __attribute__((ext_vector_type(8)));
typedef float fx4 __attribute__((ext_vector_type(4)));
typedef u16 ux8 __attribute__((ext_vector_type(8)));

__device__ __forceinline__ u16 f2bf(float f) {
  union { float f; unsigned u; } x; x.f = f;
  unsigned r = x.u + 0x7fffu + ((x.u >> 16) & 1u);
  return (u16)(r >> 16);
}
__device__ __forceinline__ float bf2f(u16 v) {
  union { unsigned u; float f; } x; x.u = ((unsigned)v) << 16;
  return x.f;
}

__device__ __forceinline__ void gload16(const void* g, void* l) {
  __builtin_amdgcn_global_load_lds((const __attribute__((address_space(1))) void*)g,
                                   (__attribute__((address_space(3))) void*)l, 16, 0, 0);
}

// =====================================================================
// TLP GEMM (r6-proven best): 128x128 tile, BK=64, 4 waves (2x2),
// single-buffered 32 KiB LDS, 2 barriers per K-step, 3 blocks/CU.
// =====================================================================
template<int OUT_BF16, int DO_GELU, int DO_CLS>
__global__ __launch_bounds__(256, 3)
void gemm_s(const u16* __restrict__ A, const u16* __restrict__ Bt,
            const float* __restrict__ bias,
            float* __restrict__ Cf, u16* __restrict__ Cb,
            float* __restrict__ cls,
            int N, int K)
{
  __shared__ __align__(16) u16 As[128 * 64];
  __shared__ __align__(16) u16 Bs[128 * 64];
  const int tid = threadIdx.x;
  const int lane = tid & 63, w = tid >> 6;
  const int c16 = lane & 15, g = lane >> 4;
  const int wr = w >> 1, wc = w & 1;

  const int nbn = N >> 7;
  int id = blockIdx.x;
  id = (id & 7) * (gridDim.x >> 3) + (id >> 3);   // XCD swizzle (grids %8==0)
  const int bm = id / nbn, bn = id % nbn;

  const int srow = w * 8 + (lane >> 3);
  const int schunk = (lane & 7) ^ (lane >> 3);
  const u16* sA = A + (size_t)(bm * 128 + srow) * K + schunk * 8;
  const u16* sB = Bt + (size_t)(bn * 128 + srow) * K + schunk * 8;
  const int wdst = w * 512;

  fx4 acc[4][4] = {};

  for (int k0 = 0; k0 < K; k0 += 64) {
    #pragma unroll
    for (int i = 0; i < 4; i++) {
      gload16(sA + (size_t)(i * 32) * K + k0, &As[i * 2048 + wdst]);
      gload16(sB + (size_t)(i * 32) * K + k0, &Bs[i * 2048 + wdst]);
    }
    __syncthreads();
    #pragma unroll
    for (int h = 0; h < 2; h++) {
      bx8 af[4], bf[4];
      #pragma unroll
      for (int m = 0; m < 4; m++) {
        const int row = wr * 64 + m * 16 + c16;
        af[m] = *(const bx8*)&As[row * 64 + (((h << 2) + g) ^ (c16 & 7)) * 8];
      }
      #pragma unroll
      for (int n = 0; n < 4; n++) {
        const int row = wc * 64 + n * 16 + c16;
        bf[n] = *(const bx8*)&Bs[row * 64 + (((h << 2) + g) ^ (c16 & 7)) * 8];
      }
      #pragma unroll
      for (int m = 0; m < 4; m++)
        #pragma unroll
        for (int n = 0; n < 4; n++)
          acc[m][n] = __builtin_amdgcn_mfma_f32_16x16x32_bf16(af[m], bf[n], acc[m][n], 0, 0, 0);
    }
    __syncthreads();
  }

  const int row0 = bm * 128 + wr * 64 + g * 4;
  const int col0 = bn * 128 + wc * 64 + c16;
  #pragma unroll
  for (int n = 0; n < 4; n++) {
    const int col = col0 + n * 16;
    const float bb = bias[col];
    #pragma unroll
    for (int m = 0; m < 4; m++) {
      #pragma unroll
      for (int r = 0; r < 4; r++) {
        float y = acc[m][n][r] + bb;
        if (DO_GELU) {
          const float tt = y;
          y = 0.5f * tt * (1.0f + tanhf(0.7978845608f * (tt + 0.044715f * tt * tt * tt)));
        }
        const int row = row0 + m * 16 + r;
        const size_t idx = (size_t)row * N + col;
        if (OUT_BF16) Cb[idx] = f2bf(y);
        else Cf[idx] = y;
        if (DO_CLS) {
          if ((row & (L_SEQ - 1)) == 0)
            cls[(row >> 12) * OUT_DIM + col] = y;
        }
      }
    }
  }
}

// =====================================================================
// Fused attention: blocks [0,768) = local windowed attention (r14
// structure, unchanged); blocks [768,960) = global-row split-flash
// segments (24 heads x 8 segments of 512 keys), filling local-attn's
// tail CUs and replacing the attn_g_score/attn_g_pv dispatches.
// Split-flash: per segment emit (m_loc, l_loc, 8x partial-o normalized
// to m_loc); combine rescales by exp(m_loc - M). Deterministic.
// =====================================================================
#define P2_STR 64   /* u16 row stride of per-wave P tile (64 keys) */

__global__ __launch_bounds__(512, 2)
void attn_fused_kernel(const u16* __restrict__ qkv, const int* __restrict__ amask,
                       u16* __restrict__ attnout,
                       float* __restrict__ gpm, float* __restrict__ gps,
                       float* __restrict__ gpo)
{
  __shared__ __align__(16) u16 Klds[2][64 * 64];       // K [key][d], swizzled
  __shared__ __align__(16) u16 Vlds[2][64 * 64];       // V^T [d][key], swizzled
  __shared__ __align__(16) u16 Plds[8 * 16 * P2_STR];  // per-wave P

  const int tid = threadIdx.x;
  const int lane = tid & 63, w = tid >> 6;

  // ---------------- global-row split-flash branch ----------------
  if (blockIdx.x >= NLOC) {
    float* fsc = (float*)&Klds[0][0];
    float* qs  = fsc;         // 64
    float* es  = fsc + 64;    // 512
    float* red = fsc + 576;   // 8
    const int idx = blockIdx.x - NLOC;
    const int bh = idx >> 3, seg = idx & 7;
    const int b = bh / N_HEADS, h = bh % N_HEADS;
    const u16* base = qkv + (size_t)b * L_SEQ * QKV_LD + h * D_HEAD;

    if (tid < D_HEAD) qs[tid] = bf2f(base[tid]);
    __syncthreads();

    const int key = seg * 512 + tid;
    const ux8* kp = (const ux8*)(base + (size_t)key * QKV_LD + H_DIM);
    float dot = 0.f;
    #pragma unroll
    for (int i = 0; i < 8; i++) {
      const ux8 kv = kp[i];
      #pragma unroll
      for (int j = 0; j < 8; j++) dot += qs[i * 8 + j] * bf2f(kv[j]);
    }
    float sv = dot * 0.125f;
    if (amask[b * L_SEQ + key] == 0) sv = -1.0e9f;

    // block max (8 waves)
    float mv = sv;
    #pragma unroll
    for (int off = 32; off > 0; off >>= 1) mv = fmaxf(mv, __shfl_xor(mv, off));
    if (lane == 0) red[w] = mv;
    __syncthreads();
    float M = -3.0e38f;
    #pragma unroll
    for (int i = 0; i < 8; i++) M = fmaxf(M, red[i]);

    const float e = __expf(sv - M);
    es[tid] = e;
    float s = e;
    #pragma unroll
    for (int off = 32; off > 0; off >>= 1) s += __shfl_xor(s, off);
    __syncthreads();            // red reads (max) + es writes done
    if (lane == 0) red[w] = s;
    __syncthreads();
    float Sl = 0.f;
    #pragma unroll
    for (int i = 0; i < 8; i++) Sl += red[i];

    // partial o: group gi (64 keys) x 64 d
    const int gi = tid >> 6, d = lane;
    const u16* vb = base + 2 * H_DIM + d;
    float acc = 0.f;
    #pragma unroll 4
    for (int i = 0; i < 64; i++) {
      const int kk = seg * 512 + gi * 64 + i;
      acc += es[gi * 64 + i] * bf2f(vb[(size_t)kk * QKV_LD]);
    }
    gpo[(((size_t)bh * NGSEG + seg) * 8 + gi) * D_HEAD + d] = acc;
    if (tid == 0) { gpm[bh * NGSEG + seg] = M; gps[bh * NGSEG + seg] = Sl; }
    return;
  }

  // ---------------- local windowed attention branch (r14) ----------------
  const int c16 = lane & 15, g = lane >> 4;
  const int bh = blockIdx.x >> 5;
  const int n = blockIdx.x & 31;
  const int b = bh / N_HEADS, h = bh % N_HEADS;

  const u16* qkvb = qkv + (size_t)b * L_SEQ * QKV_LD + h * D_HEAD;
  const int chunk_lo = n * CHUNK - CHUNK;

  const int qrow = n * CHUNK + w * 16 + c16;
  const u16* qp = qkvb + (size_t)qrow * QKV_LD + g * 8;
  const bx8 aq0 = *(const bx8*)qp;
  const bx8 aq1 = *(const bx8*)(qp + 32);

  unsigned kvm = 0;
  #pragma unroll
  for (int kf = 0; kf < 24; kf++) {
    const int pos = chunk_lo + kf * 16 + c16;
    bool ok = (pos >= 1) && (pos < L_SEQ);
    if (ok) ok = (amask[b * L_SEQ + pos] > 0);
    kvm |= ((unsigned)ok) << kf;
  }

  const int cq = w * 16 + g * 4;

  float m[4], l[4], pgv[4];
  {
    const u16* kp = qkvb + H_DIM + g * 8;   // pos 0
    const bx8 b0 = *(const bx8*)kp;
    const bx8 b1 = *(const bx8*)(kp + 32);
    fx4 sg = {};
    sg = __builtin_amdgcn_mfma_f32_16x16x32_bf16(aq0, b0, sg, 0, 0, 0);
    sg = __builtin_amdgcn_mfma_f32_16x16x32_bf16(aq1, b1, sg, 0, 0, 0);
    #pragma unroll
    for (int r = 0; r < 4; r++) {
      const float val = (c16 == 0) ? sg[r] * 0.125f : -1.0e9f;
      float mm = val;
      mm = fmaxf(mm, __shfl_xor(mm, 1));
      mm = fmaxf(mm, __shfl_xor(mm, 2));
      mm = fmaxf(mm, __shfl_xor(mm, 4));
      mm = fmaxf(mm, __shfl_xor(mm, 8));
      m[r] = mm;
      pgv[r] = __expf(val - mm);
      float t = pgv[r];
      t += __shfl_xor(t, 1);
      t += __shfl_xor(t, 2);
      t += __shfl_xor(t, 4);
      t += __shfl_xor(t, 8);
      l[r] = t;
    }
  }

  const int krow_s = w * 8 + (lane >> 3);
  const int ksc = (lane & 7) ^ (krow_s & 7);
  const int d = lane;
  const int vdst = d * 64 + ((w ^ (d & 7)) << 3);

  {
    int pos = chunk_lo + krow_s;
    if (pos < 0) pos = 0;
    if (pos >= L_SEQ) pos = L_SEQ - 1;
    gload16(qkvb + (size_t)pos * QKV_LD + H_DIM + ksc * 8, &Klds[0][w * 512]);
  }
  ux8 vreg;
  #pragma unroll
  for (int j = 0; j < 8; j++) {
    int pos = chunk_lo + w * 8 + j;
    if (pos < 0) pos = 0;
    if (pos >= L_SEQ) pos = L_SEQ - 1;
    vreg[j] = qkvb[(size_t)pos * QKV_LD + 2 * H_DIM + d];
  }
  *(ux8*)&Vlds[0][vdst] = vreg;
  __syncthreads();

  fx4 o[4] = {};
  u16* pb = Plds + w * 16 * P2_STR;
  const int prow = (w * 16 + c16) * P2_STR;

  for (int t = 0; t < 6; t++) {
    const int cur = t & 1, nxt = cur ^ 1;

    if (t < 5) {
      int pos = chunk_lo + (t + 1) * 64 + krow_s;
      if (pos < 0) pos = 0;
      if (pos >= L_SEQ) pos = L_SEQ - 1;
      gload16(qkvb + (size_t)pos * QKV_LD + H_DIM + ksc * 8, &Klds[nxt][w * 512]);
      #pragma unroll
      for (int j = 0; j < 8; j++) {
        int vp = chunk_lo + (t + 1) * 64 + w * 8 + j;
        if (vp < 0) vp = 0;
        if (vp >= L_SEQ) vp = L_SEQ - 1;
        vreg[j] = qkvb[(size_t)vp * QKV_LD + 2 * H_DIM + d];
      }
    }

    fx4 s[4];
    __builtin_amdgcn_s_setprio(1);
    #pragma unroll
    for (int kf = 0; kf < 4; kf++) {
      const int krow = kf * 16 + c16;
      const bx8 b0 = *(const bx8*)&Klds[cur][krow * 64 + ((g ^ (c16 & 7)) << 3)];
      const bx8 b1 = *(const bx8*)&Klds[cur][krow * 64 + (((4 + g) ^ (c16 & 7)) << 3)];
      fx4 a = {};
      a = __builtin_amdgcn_mfma_f32_16x16x32_bf16(aq0, b0, a, 0, 0, 0);
      a = __builtin_amdgcn_mfma_f32_16x16x32_bf16(aq1, b1, a, 0, 0, 0);
      s[kf] = a;
    }
    __builtin_amdgcn_s_setprio(0);
    float pmax[4];
    #pragma unroll
    for (int r = 0; r < 4; r++) pmax[r] = -3.0e38f;
    #pragma unroll
    for (int kf = 0; kf < 4; kf++) {
      const int KF = t * 4 + kf;
      const int j = KF * 16 + c16;
      const bool kv = ((kvm >> KF) & 1u) != 0;
      #pragma unroll
      for (int r = 0; r < 4; r++) {
        const int c = cq + r;
        const bool keep = kv && (j >= c && j <= c + 256);
        const float val = keep ? s[kf][r] * 0.125f : -1.0e9f;
        s[kf][r] = val;
        pmax[r] = fmaxf(pmax[r], val);
      }
    }
    #pragma unroll
    for (int r = 0; r < 4; r++) {
      float mm = pmax[r];
      mm = fmaxf(mm, __shfl_xor(mm, 1));
      mm = fmaxf(mm, __shfl_xor(mm, 2));
      mm = fmaxf(mm, __shfl_xor(mm, 4));
      mm = fmaxf(mm, __shfl_xor(mm, 8));
      const float newm = fmaxf(m[r], mm);
      const float scale = __expf(m[r] - newm);
      m[r] = newm;
      l[r] *= scale;
      pgv[r] *= scale;
      #pragma unroll
      for (int df = 0; df < 4; df++) o[df][r] *= scale;
    }
    float lsum[4] = {0.f, 0.f, 0.f, 0.f};
    #pragma unroll
    for (int kf = 0; kf < 4; kf++)
      #pragma unroll
      for (int r = 0; r < 4; r++) {
        const float p = __expf(s[kf][r] - m[r]);
        s[kf][r] = p;
        lsum[r] += p;
      }
    #pragma unroll
    for (int r = 0; r < 4; r++) {
      float tt = lsum[r];
      tt += __shfl_xor(tt, 1);
      tt += __shfl_xor(tt, 2);
      tt += __shfl_xor(tt, 4);
      tt += __shfl_xor(tt, 8);
      l[r] += tt;
    }
    #pragma unroll
    for (int kf = 0; kf < 4; kf++) {
      #pragma unroll
      for (int r = 0; r < 4; r++) {
        const int rr = g * 4 + r;
        const int jj = kf * 16 + c16;
        pb[rr * P2_STR + (((jj >> 3) ^ (rr & 7)) << 3) + (jj & 7)] = f2bf(s[kf][r]);
      }
    }
    __builtin_amdgcn_s_setprio(1);
    #pragma unroll
    for (int kt = 0; kt < 2; kt++) {
      const int ckp = kt * 4 + g;
      const bx8 pa = *(const bx8*)&Plds[prow + ((ckp ^ (c16 & 7)) << 3)];
      #pragma unroll
      for (int df = 0; df < 4; df++) {
        const int vrow = df * 16 + c16;
        const bx8 vvf = *(const bx8*)&Vlds[cur][vrow * 64 + ((ckp ^ (c16 & 7)) << 3)];
        o[df] = __builtin_amdgcn_mfma_f32_16x16x32_bf16(pa, vvf, o[df], 0, 0, 0);
      }
    }
    __builtin_amdgcn_s_setprio(0);
    if (t < 5) *(ux8*)&Vlds[nxt][vdst] = vreg;
    __syncthreads();
  }

  float rinv[4], pg[4];
  #pragma unroll
  for (int r = 0; r < 4; r++) {
    rinv[r] = 1.0f / l[r];
    pg[r] = __shfl(pgv[r], g * 16);
  }
  u16* ob = attnout + (size_t)b * L_SEQ * H_DIM + h * D_HEAD;
  const int posq = n * CHUNK + w * 16 + g * 4;
  #pragma unroll
  for (int df = 0; df < 4; df++) {
    const float v0f = bf2f(qkvb[2 * H_DIM + df * 16 + c16]);
    #pragma unroll
    for (int r = 0; r < 4; r++)
      ob[(size_t)(posq + r) * H_DIM + df * 16 + c16] =
          f2bf((o[df][r] + pg[r] * v0f) * rinv[r]);
  }
}

// combine split-flash partials -> query row 0 (runs after attn_fused)
__global__ __launch_bounds__(64)
void attn_g_combine(const float* __restrict__ gpm, const float* __restrict__ gps,
                    const float* __restrict__ gpo, u16* __restrict__ attnout)
{
  const int bh = blockIdx.x;
  const int b = bh / N_HEADS, h = bh % N_HEADS;
  const int d = threadIdx.x;
  float M = -3.0e38f;
  #pragma unroll
  for (int s = 0; s < NGSEG; s++) M = fmaxf(M, gpm[bh * NGSEG + s]);
  float S = 0.f, acc = 0.f;
  #pragma unroll
  for (int s = 0; s < NGSEG; s++) {
    const float sc = __expf(gpm[bh * NGSEG + s] - M);
    S += gps[bh * NGSEG + s] * sc;
    #pragma unroll
    for (int gi = 0; gi < 8; gi++)
      acc += gpo[(((size_t)bh * NGSEG + s) * 8 + gi) * D_HEAD + d] * sc;
  }
  attnout[(size_t)b * L_SEQ * H_DIM + h * D_HEAD + d] = f2bf(acc / S);
}

// ---------------- LayerNorm (bf16 residual stream) ----------------
__device__ __forceinline__ void block_stats(float sum, float sq, float* red,
                                            float& mean, float& rstd)
{
  const int lane = threadIdx.x & 63, wv = threadIdx.x >> 6;
  #pragma unroll
  for (int off = 32; off > 0; off >>= 1) {
    sum += __shfl_xor(sum, off);
    sq  += __shfl_xor(sq, off);
  }
  if (lane == 0) { red[wv] = sum; red[4 + wv] = sq; }
  __syncthreads();
  sum = red[0] + red[1] + red[2] + red[3];
  sq  = red[4] + red[5] + red[6] + red[7];
  mean = sum * (1.0f / H_DIM);
  const float var = sq * (1.0f / H_DIM) - mean * mean;
  rstd = rsqrtf(var + EPS_LN);
}

__global__ __launch_bounds__(256)
void add_ln_kernel(u16* xio, const u16* __restrict__ yin,
                   const float* __restrict__ gam, const float* __restrict__ bet)
{
  __shared__ float red[8];
  const int row = blockIdx.x, tid = threadIdx.x;
  float v[3]; float sum = 0.f, sq = 0.f;
  #pragma unroll
  for (int i = 0; i < 3; i++) {
    const int c = tid + i * 256;
    const float t = bf2f(xio[(size_t)row * H_DIM + c]) + bf2f(yin[(size_t)row * H_DIM + c]);
    v[i] = t; sum += t; sq += t * t;
  }
  float mean, rstd;
  block_stats(sum, sq, red, mean, rstd);
  #pragma unroll
  for (int i = 0; i < 3; i++) {
    const int c = tid + i * 256;
    const float y = (v[i] - mean) * rstd * gam[c] + bet[c];
    xio[(size_t)row * H_DIM + c] = f2bf(y);
  }
}

// ---------------- Fused weight prep + embed_ln (one launch) ----------------
// blocks [0,14112): weight transposes; [14112,14130): bias concat;
// [14130, 14130+8192): embed+LN rows.
__global__ __launch_bounds__(256)
void prep_embed(const float* __restrict__ Wq, const float* __restrict__ Wk,
                const float* __restrict__ Wv, const float* __restrict__ Wo,
                const float* __restrict__ W1, const float* __restrict__ W2,
                const float* __restrict__ Wfc,
                const float* __restrict__ bq, const float* __restrict__ bk,
                const float* __restrict__ bv,
                u16* __restrict__ wqkvT, u16* __restrict__ woT,
                u16* __restrict__ w1T, u16* __restrict__ w2T,
                u16* __restrict__ wfcT, float* __restrict__ bqkv,
                const int* __restrict__ ids, const float* __restrict__ wemb,
                const float* __restrict__ pemb, const float* __restrict__ gam,
                const float* __restrict__ bet, u16* __restrict__ xb)
{
  const int t = blockIdx.x;
  const int tid = threadIdx.x;
  __shared__ float tile[32][33];   // also hosts red[8] for embed branch

  if (t >= 14130) {   // ---- embed + LN ----
    const int row = t - 14130;
    const int l = row & (L_SEQ - 1);
    const int id = ids[row];
    float v[3]; float sum = 0.f, sq = 0.f;
    #pragma unroll
    for (int i = 0; i < 3; i++) {
      const int c = tid + i * 256;
      const float x = wemb[(size_t)id * H_DIM + c] + pemb[(size_t)l * H_DIM + c];
      v[i] = x; sum += x; sq += x * x;
    }
    float mean, rstd;
    block_stats(sum, sq, &tile[0][0], mean, rstd);
    #pragma unroll
    for (int i = 0; i < 3; i++) {
      const int c = tid + i * 256;
      const float y = (v[i] - mean) * rstd * gam[c] + bet[c];
      xb[(size_t)row * H_DIM + c] = f2bf(y);
    }
    return;
  }
  if (t >= 14112) {   // ---- bias concat ----
    const int idx = t - 14112;
    const int l = idx / 9, j = idx % 9;
    const int i = j * 256 + tid;
    if (i < H_DIM)          bqkv[l * QKV_LD + i] = bq[l * H_DIM + i];
    else if (i < 2 * H_DIM) bqkv[l * QKV_LD + i] = bk[l * H_DIM + i - H_DIM];
    else if (i < 3 * H_DIM) bqkv[l * QKV_LD + i] = bv[l * H_DIM + i - 2 * H_DIM];
    return;
  }
  // ---- weight transpose ----
  const float* src; u16* dst; int K, N, r;
  if (t < 13824) {
    const int l = t / 6912; r = t % 6912;
    if (r < 2304) {
      const int mq = r / 576; r = r % 576; K = H_DIM; N = H_DIM;
      if (mq == 0)      src = Wq + (size_t)l * H_DIM * H_DIM;
      else if (mq == 1) src = Wk + (size_t)l * H_DIM * H_DIM;
      else if (mq == 2) src = Wv + (size_t)l * H_DIM * H_DIM;
      else              src = Wo + (size_t)l * H_DIM * H_DIM;
      dst = (mq < 3) ? wqkvT + (size_t)l * QKV_LD * H_DIM + (size_t)mq * H_DIM * H_DIM
                     : woT + (size_t)l * H_DIM * H_DIM;
    } else if (r < 4608) {
      r -= 2304; K = H_DIM; N = FF_DIM;
      src = W1 + (size_t)l * H_DIM * FF_DIM;
      dst = w1T + (size_t)l * FF_DIM * H_DIM;
    } else {
      r -= 4608; K = FF_DIM; N = H_DIM;
      src = W2 + (size_t)l * FF_DIM * H_DIM;
      dst = w2T + (size_t)l * H_DIM * FF_DIM;
    }
  } else {
    r = t - 13824; K = H_DIM; N = OUT_DIM; src = Wfc; dst = wfcT;
  }
  const int ntn = N >> 5;
  const int k0 = (r / ntn) * 32, n0 = (r % ntn) * 32;
  const int tx = tid & 31, ty = tid >> 5;
  #pragma unroll
  for (int i = 0; i < 32; i += 8)
    tile[ty + i][tx] = src[(size_t)(k0 + ty + i) * N + n0 + tx];
  __syncthreads();
  #pragma unroll
  for (int i = 0; i < 32; i += 8)
    dst[(size_t)(n0 + ty + i) * K + k0 + tx] = f2bf(tile[tx][ty + i]);
}

// ---------------- host ----------------
extern "C" void kernel_launch(void* const* d_in, const int* in_sizes, int n_in,
                              void* d_out, int out_size, void* d_ws, size_t ws_size,
                              hipStream_t stream)
{
  (void)in_sizes; (void)n_in; (void)out_size; (void)ws_size;
  const int*   ids   = (const int*)d_in[0];
  const int*   amask = (const int*)d_in[1];
  const float* wemb  = (const float*)d_in[2];
  const float* pemb  = (const float*)d_in[3];
  const float* elns  = (const float*)d_in[4];
  const float* elnb  = (const float*)d_in[5];
  const float* Wq    = (const float*)d_in[6];
  const float* bq    = (const float*)d_in[7];
  const float* Wk    = (const float*)d_in[8];
  const float* bk    = (const float*)d_in[9];
  const float* Wv    = (const float*)d_in[10];
  const float* bv    = (const float*)d_in[11];
  const float* Wo    = (const float*)d_in[12];
  const float* bo    = (const float*)d_in[13];
  const float* ln1s  = (const float*)d_in[14];
  const float* ln1b  = (const float*)d_in[15];
  const float* W1    = (const float*)d_in[16];
  const float* b1    = (const float*)d_in[17];
  const float* W2    = (const float*)d_in[18];
  const float* b2    = (const float*)d_in[19];
  const float* ln2s  = (const float*)d_in[20];
  const float* ln2b  = (const float*)d_in[21];
  const float* Wfc   = (const float*)d_in[22];
  const float* bfc   = (const float*)d_in[23];

  char* ws = (char*)d_ws;
  size_t off = 0;
  auto alloc = [&](size_t bytes) -> void* {
    void* p = ws + off;
    off += (bytes + 255) & ~(size_t)255;
    return p;
  };
  u16* xb     = (u16*)alloc((size_t)M_ROWS * H_DIM * 2);   // residual stream (post-LN)
  u16* projb  = (u16*)alloc((size_t)M_ROWS * H_DIM * 2);
  u16* big    = (u16*)alloc((size_t)M_ROWS * FF_DIM * 2);  // qkv / ff1 time-share
  u16* attno  = (u16*)alloc((size_t)M_ROWS * H_DIM * 2);
  u16* wqkvT  = (u16*)alloc((size_t)2 * QKV_LD * H_DIM * 2);
  u16* woT    = (u16*)alloc((size_t)2 * H_DIM * H_DIM * 2);
  u16* w1T    = (u16*)alloc((size_t)2 * FF_DIM * H_DIM * 2);
  u16* w2T    = (u16*)alloc((size_t)2 * H_DIM * FF_DIM * 2);
  u16* wfcT   = (u16*)alloc((size_t)OUT_DIM * H_DIM * 2);
  float* bqkv = (float*)alloc(2 * QKV_LD * 4);
  float* gpm  = (float*)alloc((size_t)BATCH * N_HEADS * NGSEG * 4);
  float* gps  = (float*)alloc((size_t)BATCH * N_HEADS * NGSEG * 4);
  float* gpo  = (float*)alloc((size_t)BATCH * N_HEADS * NGSEG * 8 * D_HEAD * 4);

  u16* qkvb = big;
  u16* ff1  = big;

  prep_embed<<<14130 + M_ROWS, 256, 0, stream>>>(
      Wq, Wk, Wv, Wo, W1, W2, Wfc, bq, bk, bv,
      wqkvT, woT, w1T, w2T, wfcT, bqkv,
      ids, wemb, pemb, elns, elnb, xb);

  for (int l = 0; l < 2; l++) {
    gemm_s<1, 0, 0><<<(M_ROWS / 128) * (QKV_LD / 128), 256, 0, stream>>>(
        xb, wqkvT + (size_t)l * QKV_LD * H_DIM, bqkv + l * QKV_LD,
        nullptr, qkvb, nullptr, QKV_LD, H_DIM);
    attn_fused_kernel<<<NLOC + BATCH * N_HEADS * NGSEG, 512, 0, stream>>>(
        qkvb, amask, attno, gpm, gps, gpo);
    attn_g_combine<<<BATCH * N_HEADS, 64, 0, stream>>>(gpm, gps, gpo, attno);
    gemm_s<1, 0, 0><<<(M_ROWS / 128) * (H_DIM / 128), 256, 0, stream>>>(
        attno, woT + (size_t)l * H_DIM * H_DIM, bo + l * H_DIM,
        nullptr, projb, nullptr, H_DIM, H_DIM);
    add_ln_kernel<<<M_ROWS, 256, 0, stream>>>(xb, projb, ln1s + l * H_DIM, ln1b + l * H_DIM);
    gemm_s<1, 1, 0><<<(M_ROWS / 128) * (FF_DIM / 128), 256, 0, stream>>>(
        xb, w1T + (size_t)l * FF_DIM * H_DIM, b1 + l * FF_DIM,
        nullptr, ff1, nullptr, FF_DIM, H_DIM);
    gemm_s<1, 0, 0><<<(M_ROWS / 128) * (H_DIM / 128), 256, 0, stream>>>(
        ff1, w2T + (size_t)l * H_DIM * FF_DIM, b2 + l * H_DIM,
        nullptr, projb, nullptr, H_DIM, FF_DIM);
    add_ln_kernel<<<M_ROWS, 256, 0, stream>>>(xb, projb, ln2s + l * H_DIM, ln2b + l * H_DIM);
  }

  float* vdn = (float*)d_out;
  float* cls = vdn + (size_t)BATCH * L_SEQ * OUT_DIM;
  gemm_s<0, 0, 1><<<(M_ROWS / 128) * (OUT_DIM / 128), 256, 0, stream>>>(
      xb, wfcT, bfc, vdn, nullptr, cls, OUT_DIM, H_DIM);
}

// Round 16
// 557.118 us; speedup vs baseline: 1.0622x; 1.0622x over previous
//
#include <hip/hip_runtime.h>
#include <hip/hip_bf16.h>
#include <stdint.h>

#define L_SEQ 4096
#define H_DIM 768
#define N_HEADS 12
#define D_HEAD 64
#define N_CHUNK 32
#define CHUNK 128
#define FF_DIM 3072
#define OUT_DIM 384
#define BATCH 2
#define EPS_LN 1e-5f
#define M_ROWS (BATCH * L_SEQ)   /* 8192 */
#define QKV_LD (3 * H_DIM)       /* 2304 */
#define NSEG 16                   /* global-row segments: 4096/256 */

typedef unsigned short u16;
typedef __bf16 bx8 __attribute__((ext_vector_type(8)));
typedef float fx4 __attribute__((ext_vector_type(4)));
typedef u16 ux8 __attribute__((ext_vector_type(8)));

__device__ __forceinline__ u16 f2bf(float f) {
  union { float f; unsigned u; } x; x.f = f;
  unsigned r = x.u + 0x7fffu + ((x.u >> 16) & 1u);
  return (u16)(r >> 16);
}
__device__ __forceinline__ float bf2f(u16 v) {
  union { unsigned u; float f; } x; x.u = ((unsigned)v) << 16;
  return x.f;
}

__device__ __forceinline__ void gload16(const void* g, void* l) {
  __builtin_amdgcn_global_load_lds((const __attribute__((address_space(1))) void*)g,
                                   (__attribute__((address_space(3))) void*)l, 16, 0, 0);
}

// =====================================================================
// TLP GEMM (r6 structure): 128x128 tile, BK=64, 4 waves (2x2),
// single-buffered 32 KiB LDS, 2 barriers per K-step.
// r16 change: 3 -> 4 blocks/CU (launch_bounds(256,4)); live set ~100
// VGPR fits the 128 cap; deeper inter-block TLP covers the per-K-step
// vmcnt(0) drain (m114 mechanism, the r6-proven lever).
// =====================================================================
template<int OUT_BF16, int DO_GELU, int DO_CLS>
__global__ __launch_bounds__(256, 4)
void gemm_s(const u16* __restrict__ A, const u16* __restrict__ Bt,
            const float* __restrict__ bias,
            float* __restrict__ Cf, u16* __restrict__ Cb,
            float* __restrict__ cls,
            int N, int K)
{
  __shared__ __align__(16) u16 As[128 * 64];
  __shared__ __align__(16) u16 Bs[128 * 64];
  const int tid = threadIdx.x;
  const int lane = tid & 63, w = tid >> 6;
  const int c16 = lane & 15, g = lane >> 4;
  const int wr = w >> 1, wc = w & 1;

  const int nbn = N >> 7;
  int id = blockIdx.x;
  id = (id & 7) * (gridDim.x >> 3) + (id >> 3);   // XCD swizzle (grids %8==0)
  const int bm = id / nbn, bn = id % nbn;

  const int srow = w * 8 + (lane >> 3);
  const int schunk = (lane & 7) ^ (lane >> 3);
  const u16* sA = A + (size_t)(bm * 128 + srow) * K + schunk * 8;
  const u16* sB = Bt + (size_t)(bn * 128 + srow) * K + schunk * 8;
  const int wdst = w * 512;

  fx4 acc[4][4] = {};

  for (int k0 = 0; k0 < K; k0 += 64) {
    #pragma unroll
    for (int i = 0; i < 4; i++) {
      gload16(sA + (size_t)(i * 32) * K + k0, &As[i * 2048 + wdst]);
      gload16(sB + (size_t)(i * 32) * K + k0, &Bs[i * 2048 + wdst]);
    }
    __syncthreads();
    #pragma unroll
    for (int h = 0; h < 2; h++) {
      bx8 af[4], bf[4];
      #pragma unroll
      for (int m = 0; m < 4; m++) {
        const int row = wr * 64 + m * 16 + c16;
        af[m] = *(const bx8*)&As[row * 64 + (((h << 2) + g) ^ (c16 & 7)) * 8];
      }
      #pragma unroll
      for (int n = 0; n < 4; n++) {
        const int row = wc * 64 + n * 16 + c16;
        bf[n] = *(const bx8*)&Bs[row * 64 + (((h << 2) + g) ^ (c16 & 7)) * 8];
      }
      #pragma unroll
      for (int m = 0; m < 4; m++)
        #pragma unroll
        for (int n = 0; n < 4; n++)
          acc[m][n] = __builtin_amdgcn_mfma_f32_16x16x32_bf16(af[m], bf[n], acc[m][n], 0, 0, 0);
    }
    __syncthreads();
  }

  const int row0 = bm * 128 + wr * 64 + g * 4;
  const int col0 = bn * 128 + wc * 64 + c16;
  #pragma unroll
  for (int n = 0; n < 4; n++) {
    const int col = col0 + n * 16;
    const float bb = bias[col];
    #pragma unroll
    for (int m = 0; m < 4; m++) {
      #pragma unroll
      for (int r = 0; r < 4; r++) {
        float y = acc[m][n][r] + bb;
        if (DO_GELU) {
          const float tt = y;
          y = 0.5f * tt * (1.0f + tanhf(0.7978845608f * (tt + 0.044715f * tt * tt * tt)));
        }
        const int row = row0 + m * 16 + r;
        const size_t idx = (size_t)row * N + col;
        if (OUT_BF16) Cb[idx] = f2bf(y);
        else Cf[idx] = y;
        if (DO_CLS) {
          if ((row & (L_SEQ - 1)) == 0)
            cls[(row >> 12) * OUT_DIM + col] = y;
        }
      }
    }
  }
}

// =====================================================================
// Local (windowed) attention v7 (r14 best): streamed KV tiles + T14
// issue-early / write-late + double-buffered K,V + 1 barrier/tile +
// setprio. LDS 48 KB, 2 blocks/CU, no spill.
// =====================================================================
#define P2_STR 64   /* u16 row stride of per-wave P tile (64 keys) */

__global__ __launch_bounds__(512, 2)
void attn_local_kernel(const u16* __restrict__ qkv, const int* __restrict__ amask,
                       u16* __restrict__ attnout)
{
  __shared__ __align__(16) u16 Klds[2][64 * 64];       // K [key][d], swizzled
  __shared__ __align__(16) u16 Vlds[2][64 * 64];       // V^T [d][key], swizzled
  __shared__ __align__(16) u16 Plds[8 * 16 * P2_STR];  // per-wave P

  const int tid = threadIdx.x;
  const int lane = tid & 63, w = tid >> 6;
  const int c16 = lane & 15, g = lane >> 4;

  const int bh = blockIdx.x >> 5;
  const int n = blockIdx.x & 31;
  const int b = bh / N_HEADS, h = bh % N_HEADS;

  const u16* qkvb = qkv + (size_t)b * L_SEQ * QKV_LD + h * D_HEAD;
  const int chunk_lo = n * CHUNK - CHUNK;

  const int qrow = n * CHUNK + w * 16 + c16;
  const u16* qp = qkvb + (size_t)qrow * QKV_LD + g * 8;
  const bx8 aq0 = *(const bx8*)qp;
  const bx8 aq1 = *(const bx8*)(qp + 32);

  unsigned kvm = 0;
  #pragma unroll
  for (int kf = 0; kf < 24; kf++) {
    const int pos = chunk_lo + kf * 16 + c16;
    bool ok = (pos >= 1) && (pos < L_SEQ);
    if (ok) ok = (amask[b * L_SEQ + pos] > 0);
    kvm |= ((unsigned)ok) << kf;
  }

  const int cq = w * 16 + g * 4;

  float m[4], l[4], pgv[4];
  {
    const u16* kp = qkvb + H_DIM + g * 8;   // pos 0
    const bx8 b0 = *(const bx8*)kp;
    const bx8 b1 = *(const bx8*)(kp + 32);
    fx4 sg = {};
    sg = __builtin_amdgcn_mfma_f32_16x16x32_bf16(aq0, b0, sg, 0, 0, 0);
    sg = __builtin_amdgcn_mfma_f32_16x16x32_bf16(aq1, b1, sg, 0, 0, 0);
    #pragma unroll
    for (int r = 0; r < 4; r++) {
      const float val = (c16 == 0) ? sg[r] * 0.125f : -1.0e9f;
      float mm = val;
      mm = fmaxf(mm, __shfl_xor(mm, 1));
      mm = fmaxf(mm, __shfl_xor(mm, 2));
      mm = fmaxf(mm, __shfl_xor(mm, 4));
      mm = fmaxf(mm, __shfl_xor(mm, 8));
      m[r] = mm;
      pgv[r] = __expf(val - mm);
      float t = pgv[r];
      t += __shfl_xor(t, 1);
      t += __shfl_xor(t, 2);
      t += __shfl_xor(t, 4);
      t += __shfl_xor(t, 8);
      l[r] = t;
    }
  }

  const int krow_s = w * 8 + (lane >> 3);
  const int ksc = (lane & 7) ^ (krow_s & 7);      // pre-swizzled K src chunk
  const int d = lane;                              // V staging: lane = d
  const int vdst = d * 64 + ((w ^ (d & 7)) << 3);  // V^T write pos (swizzled)

  {
    int pos = chunk_lo + krow_s;
    if (pos < 0) pos = 0;
    if (pos >= L_SEQ) pos = L_SEQ - 1;
    gload16(qkvb + (size_t)pos * QKV_LD + H_DIM + ksc * 8, &Klds[0][w * 512]);
  }
  ux8 vreg;
  #pragma unroll
  for (int j = 0; j < 8; j++) {
    int pos = chunk_lo + w * 8 + j;
    if (pos < 0) pos = 0;
    if (pos >= L_SEQ) pos = L_SEQ - 1;
    vreg[j] = qkvb[(size_t)pos * QKV_LD + 2 * H_DIM + d];
  }
  *(ux8*)&Vlds[0][vdst] = vreg;
  __syncthreads();   // K(0) drained; V(0) visible

  fx4 o[4] = {};
  u16* pb = Plds + w * 16 * P2_STR;
  const int prow = (w * 16 + c16) * P2_STR;

  for (int t = 0; t < 6; t++) {
    const int cur = t & 1, nxt = cur ^ 1;

    if (t < 5) {
      int pos = chunk_lo + (t + 1) * 64 + krow_s;
      if (pos < 0) pos = 0;
      if (pos >= L_SEQ) pos = L_SEQ - 1;
      gload16(qkvb + (size_t)pos * QKV_LD + H_DIM + ksc * 8, &Klds[nxt][w * 512]);
      #pragma unroll
      for (int j = 0; j < 8; j++) {
        int vp = chunk_lo + (t + 1) * 64 + w * 8 + j;
        if (vp < 0) vp = 0;
        if (vp >= L_SEQ) vp = L_SEQ - 1;
        vreg[j] = qkvb[(size_t)vp * QKV_LD + 2 * H_DIM + d];
      }
    }

    fx4 s[4];
    __builtin_amdgcn_s_setprio(1);
    #pragma unroll
    for (int kf = 0; kf < 4; kf++) {
      const int krow = kf * 16 + c16;                 // krow&7 == c16&7
      const bx8 b0 = *(const bx8*)&Klds[cur][krow * 64 + ((g ^ (c16 & 7)) << 3)];
      const bx8 b1 = *(const bx8*)&Klds[cur][krow * 64 + (((4 + g) ^ (c16 & 7)) << 3)];
      fx4 a = {};
      a = __builtin_amdgcn_mfma_f32_16x16x32_bf16(aq0, b0, a, 0, 0, 0);
      a = __builtin_amdgcn_mfma_f32_16x16x32_bf16(aq1, b1, a, 0, 0, 0);
      s[kf] = a;
    }
    __builtin_amdgcn_s_setprio(0);
    float pmax[4];
    #pragma unroll
    for (int r = 0; r < 4; r++) pmax[r] = -3.0e38f;
    #pragma unroll
    for (int kf = 0; kf < 4; kf++) {
      const int KF = t * 4 + kf;
      const int j = KF * 16 + c16;
      const bool kv = ((kvm >> KF) & 1u) != 0;
      #pragma unroll
      for (int r = 0; r < 4; r++) {
        const int c = cq + r;
        const bool keep = kv && (j >= c && j <= c + 256);
        const float val = keep ? s[kf][r] * 0.125f : -1.0e9f;
        s[kf][r] = val;
        pmax[r] = fmaxf(pmax[r], val);
      }
    }
    #pragma unroll
    for (int r = 0; r < 4; r++) {
      float mm = pmax[r];
      mm = fmaxf(mm, __shfl_xor(mm, 1));
      mm = fmaxf(mm, __shfl_xor(mm, 2));
      mm = fmaxf(mm, __shfl_xor(mm, 4));
      mm = fmaxf(mm, __shfl_xor(mm, 8));
      const float newm = fmaxf(m[r], mm);
      const float scale = __expf(m[r] - newm);
      m[r] = newm;
      l[r] *= scale;
      pgv[r] *= scale;
      #pragma unroll
      for (int df = 0; df < 4; df++) o[df][r] *= scale;
    }
    float lsum[4] = {0.f, 0.f, 0.f, 0.f};
    #pragma unroll
    for (int kf = 0; kf < 4; kf++)
      #pragma unroll
      for (int r = 0; r < 4; r++) {
        const float p = __expf(s[kf][r] - m[r]);
        s[kf][r] = p;
        lsum[r] += p;
      }
    #pragma unroll
    for (int r = 0; r < 4; r++) {
      float tt = lsum[r];
      tt += __shfl_xor(tt, 1);
      tt += __shfl_xor(tt, 2);
      tt += __shfl_xor(tt, 4);
      tt += __shfl_xor(tt, 8);
      l[r] += tt;
    }
    #pragma unroll
    for (int kf = 0; kf < 4; kf++) {
      #pragma unroll
      for (int r = 0; r < 4; r++) {
        const int rr = g * 4 + r;
        const int jj = kf * 16 + c16;       // 0..63 within tile
        pb[rr * P2_STR + (((jj >> 3) ^ (rr & 7)) << 3) + (jj & 7)] = f2bf(s[kf][r]);
      }
    }
    __builtin_amdgcn_s_setprio(1);
    #pragma unroll
    for (int kt = 0; kt < 2; kt++) {
      const int ckp = kt * 4 + g;           // chunk 0..7
      const bx8 pa = *(const bx8*)&Plds[prow + ((ckp ^ (c16 & 7)) << 3)];
      #pragma unroll
      for (int df = 0; df < 4; df++) {
        const int vrow = df * 16 + c16;
        const bx8 vvf = *(const bx8*)&Vlds[cur][vrow * 64 + ((ckp ^ (c16 & 7)) << 3)];
        o[df] = __builtin_amdgcn_mfma_f32_16x16x32_bf16(pa, vvf, o[df], 0, 0, 0);
      }
    }
    __builtin_amdgcn_s_setprio(0);
    if (t < 5) *(ux8*)&Vlds[nxt][vdst] = vreg;
    __syncthreads();
  }

  float rinv[4], pg[4];
  #pragma unroll
  for (int r = 0; r < 4; r++) {
    rinv[r] = 1.0f / l[r];
    pg[r] = __shfl(pgv[r], g * 16);
  }
  u16* ob = attnout + (size_t)b * L_SEQ * H_DIM + h * D_HEAD;
  const int posq = n * CHUNK + w * 16 + g * 4;
  #pragma unroll
  for (int df = 0; df < 4; df++) {
    const float v0f = bf2f(qkvb[2 * H_DIM + df * 16 + c16]);
    #pragma unroll
    for (int r = 0; r < 4; r++)
      ob[(size_t)(posq + r) * H_DIM + df * 16 + c16] =
          f2bf((o[df][r] + pg[r] * v0f) * rinv[r]);
  }
}

// ---------------- Global row (query position 0) ----------------
__global__ __launch_bounds__(256)
void attn_g_score(const u16* __restrict__ qkv, const int* __restrict__ amask,
                  float* __restrict__ sbuf, float* __restrict__ pmax)
{
  __shared__ float qs[D_HEAD];
  __shared__ float red[4];
  const int seg = blockIdx.x, bh = blockIdx.y;
  const int b = bh / N_HEADS, h = bh % N_HEADS;
  const u16* base = qkv + (size_t)b * L_SEQ * QKV_LD + h * D_HEAD;
  const int tid = threadIdx.x;

  if (tid < D_HEAD) qs[tid] = bf2f(base[tid]);
  __syncthreads();

  const int l = seg * 256 + tid;
  const ux8* kp = (const ux8*)(base + (size_t)l * QKV_LD + H_DIM);
  float dot = 0.f;
  #pragma unroll
  for (int i = 0; i < 8; i++) {
    const ux8 kv = kp[i];
    #pragma unroll
    for (int j = 0; j < 8; j++) dot += qs[i * 8 + j] * bf2f(kv[j]);
  }
  float sv = dot * 0.125f;
  if (amask[b * L_SEQ + l] == 0) sv = -1.0e9f;
  sbuf[(size_t)bh * L_SEQ + l] = sv;

  float m = sv;
  #pragma unroll
  for (int off = 32; off > 0; off >>= 1) m = fmaxf(m, __shfl_xor(m, off));
  if ((tid & 63) == 0) red[tid >> 6] = m;
  __syncthreads();
  if (tid == 0)
    pmax[bh * NSEG + seg] = fmaxf(fmaxf(red[0], red[1]), fmaxf(red[2], red[3]));
}

__global__ __launch_bounds__(256)
void attn_g_pv(const u16* __restrict__ qkv, const float* __restrict__ sbuf,
               const float* __restrict__ pmax, float* __restrict__ psum,
               float* __restrict__ po)
{
  __shared__ float es[256];
  __shared__ float red[4];
  const int seg = blockIdx.x, bh = blockIdx.y;
  const int b = bh / N_HEADS, h = bh % N_HEADS;
  const int tid = threadIdx.x;

  float M = -3.0e38f;
  #pragma unroll
  for (int i = 0; i < NSEG; i++) M = fmaxf(M, pmax[bh * NSEG + i]);

  const int l = seg * 256 + tid;
  const float e = __expf(sbuf[(size_t)bh * L_SEQ + l] - M);
  es[tid] = e;

  float t = e;
  #pragma unroll
  for (int off = 32; off > 0; off >>= 1) t += __shfl_xor(t, off);
  if ((tid & 63) == 0) red[tid >> 6] = t;
  __syncthreads();
  if (tid == 0) psum[bh * NSEG + seg] = red[0] + red[1] + red[2] + red[3];

  const int d = tid & 63, grp = tid >> 6;
  const u16* vb = qkv + (size_t)b * L_SEQ * QKV_LD + h * D_HEAD + 2 * H_DIM + d;
  float acc = 0.f;
  #pragma unroll 4
  for (int i = 0; i < 64; i++) {
    const int ll = seg * 256 + grp * 64 + i;
    acc += es[grp * 64 + i] * bf2f(vb[(size_t)ll * QKV_LD]);
  }
  po[(((size_t)bh * NSEG + seg) * 4 + grp) * D_HEAD + d] = acc;
}

__global__ __launch_bounds__(64)
void attn_g_combine(const float* __restrict__ psum, const float* __restrict__ po,
                    u16* __restrict__ attnout)
{
  const int bh = blockIdx.x;
  const int b = bh / N_HEADS, h = bh % N_HEADS;
  const int d = threadIdx.x;
  float S = 0.f;
  #pragma unroll
  for (int i = 0; i < NSEG; i++) S += psum[bh * NSEG + i];
  float acc = 0.f;
  #pragma unroll
  for (int i = 0; i < NSEG * 4; i++)
    acc += po[((size_t)bh * NSEG * 4 + i) * D_HEAD + d];
  attnout[(size_t)b * L_SEQ * H_DIM + h * D_HEAD + d] = f2bf(acc / S);
}

// ---------------- LayerNorm kernels (bf16 residual stream) ----------------
__device__ __forceinline__ void block_stats(float sum, float sq, float* red,
                                            float& mean, float& rstd)
{
  const int lane = threadIdx.x & 63, wv = threadIdx.x >> 6;
  #pragma unroll
  for (int off = 32; off > 0; off >>= 1) {
    sum += __shfl_xor(sum, off);
    sq  += __shfl_xor(sq, off);
  }
  if (lane == 0) { red[wv] = sum; red[4 + wv] = sq; }
  __syncthreads();
  sum = red[0] + red[1] + red[2] + red[3];
  sq  = red[4] + red[5] + red[6] + red[7];
  mean = sum * (1.0f / H_DIM);
  const float var = sq * (1.0f / H_DIM) - mean * mean;
  rstd = rsqrtf(var + EPS_LN);
}

__global__ __launch_bounds__(256)
void embed_ln_kernel(const int* __restrict__ ids, const float* __restrict__ wemb,
                     const float* __restrict__ pemb, const float* __restrict__ gam,
                     const float* __restrict__ bet, u16* __restrict__ xb)
{
  __shared__ float red[8];
  const int row = blockIdx.x, tid = threadIdx.x;
  const int l = row & (L_SEQ - 1);
  const int id = ids[row];
  float v[3]; float sum = 0.f, sq = 0.f;
  #pragma unroll
  for (int i = 0; i < 3; i++) {
    const int c = tid + i * 256;
    const float t = wemb[(size_t)id * H_DIM + c] + pemb[(size_t)l * H_DIM + c];
    v[i] = t; sum += t; sq += t * t;
  }
  float mean, rstd;
  block_stats(sum, sq, red, mean, rstd);
  #pragma unroll
  for (int i = 0; i < 3; i++) {
    const int c = tid + i * 256;
    const float y = (v[i] - mean) * rstd * gam[c] + bet[c];
    xb[(size_t)row * H_DIM + c] = f2bf(y);
  }
}

__global__ __launch_bounds__(256)
void add_ln_kernel(u16* xio, const u16* __restrict__ yin,
                   const float* __restrict__ gam, const float* __restrict__ bet)
{
  __shared__ float red[8];
  const int row = blockIdx.x, tid = threadIdx.x;
  float v[3]; float sum = 0.f, sq = 0.f;
  #pragma unroll
  for (int i = 0; i < 3; i++) {
    const int c = tid + i * 256;
    const float t = bf2f(xio[(size_t)row * H_DIM + c]) + bf2f(yin[(size_t)row * H_DIM + c]);
    v[i] = t; sum += t; sq += t * t;
  }
  float mean, rstd;
  block_stats(sum, sq, red, mean, rstd);
  #pragma unroll
  for (int i = 0; i < 3; i++) {
    const int c = tid + i * 256;
    const float y = (v[i] - mean) * rstd * gam[c] + bet[c];
    xio[(size_t)row * H_DIM + c] = f2bf(y);
  }
}

// ---------------- Fused weight prep ----------------
__global__ __launch_bounds__(256)
void prep_weights(const float* __restrict__ Wq, const float* __restrict__ Wk,
                  const float* __restrict__ Wv, const float* __restrict__ Wo,
                  const float* __restrict__ W1, const float* __restrict__ W2,
                  const float* __restrict__ Wfc,
                  const float* __restrict__ bq, const float* __restrict__ bk,
                  const float* __restrict__ bv,
                  u16* __restrict__ wqkvT, u16* __restrict__ woT,
                  u16* __restrict__ w1T, u16* __restrict__ w2T,
                  u16* __restrict__ wfcT, float* __restrict__ bqkv)
{
  const int t = blockIdx.x;
  const int tid = threadIdx.x;
  if (t >= 14112) {   // bias concat: 18 blocks
    const int idx = t - 14112;
    const int l = idx / 9, j = idx % 9;
    const int i = j * 256 + tid;
    if (i < H_DIM)          bqkv[l * QKV_LD + i] = bq[l * H_DIM + i];
    else if (i < 2 * H_DIM) bqkv[l * QKV_LD + i] = bk[l * H_DIM + i - H_DIM];
    else if (i < 3 * H_DIM) bqkv[l * QKV_LD + i] = bv[l * H_DIM + i - 2 * H_DIM];
    return;
  }
  const float* src; u16* dst; int K, N, r;
  if (t < 13824) {
    const int l = t / 6912; r = t % 6912;
    if (r < 2304) {
      const int m = r / 576; r = r % 576; K = H_DIM; N = H_DIM;
      if (m == 0)      src = Wq + (size_t)l * H_DIM * H_DIM;
      else if (m == 1) src = Wk + (size_t)l * H_DIM * H_DIM;
      else if (m == 2) src = Wv + (size_t)l * H_DIM * H_DIM;
      else             src = Wo + (size_t)l * H_DIM * H_DIM;
      dst = (m < 3) ? wqkvT + (size_t)l * QKV_LD * H_DIM + (size_t)m * H_DIM * H_DIM
                    : woT + (size_t)l * H_DIM * H_DIM;
    } else if (r < 4608) {
      r -= 2304; K = H_DIM; N = FF_DIM;
      src = W1 + (size_t)l * H_DIM * FF_DIM;
      dst = w1T + (size_t)l * FF_DIM * H_DIM;
    } else {
      r -= 4608; K = FF_DIM; N = H_DIM;
      src = W2 + (size_t)l * FF_DIM * H_DIM;
      dst = w2T + (size_t)l * H_DIM * FF_DIM;
    }
  } else {
    r = t - 13824; K = H_DIM; N = OUT_DIM; src = Wfc; dst = wfcT;
  }
  const int ntn = N >> 5;
  const int k0 = (r / ntn) * 32, n0 = (r % ntn) * 32;
  __shared__ float tile[32][33];
  const int tx = tid & 31, ty = tid >> 5;
  #pragma unroll
  for (int i = 0; i < 32; i += 8)
    tile[ty + i][tx] = src[(size_t)(k0 + ty + i) * N + n0 + tx];
  __syncthreads();
  #pragma unroll
  for (int i = 0; i < 32; i += 8)
    dst[(size_t)(n0 + ty + i) * K + k0 + tx] = f2bf(tile[tx][ty + i]);
}

// ---------------- host ----------------
extern "C" void kernel_launch(void* const* d_in, const int* in_sizes, int n_in,
                              void* d_out, int out_size, void* d_ws, size_t ws_size,
                              hipStream_t stream)
{
  (void)in_sizes; (void)n_in; (void)out_size; (void)ws_size;
  const int*   ids   = (const int*)d_in[0];
  const int*   amask = (const int*)d_in[1];
  const float* wemb  = (const float*)d_in[2];
  const float* pemb  = (const float*)d_in[3];
  const float* elns  = (const float*)d_in[4];
  const float* elnb  = (const float*)d_in[5];
  const float* Wq    = (const float*)d_in[6];
  const float* bq    = (const float*)d_in[7];
  const float* Wk    = (const float*)d_in[8];
  const float* bk    = (const float*)d_in[9];
  const float* Wv    = (const float*)d_in[10];
  const float* bv    = (const float*)d_in[11];
  const float* Wo    = (const float*)d_in[12];
  const float* bo    = (const float*)d_in[13];
  const float* ln1s  = (const float*)d_in[14];
  const float* ln1b  = (const float*)d_in[15];
  const float* W1    = (const float*)d_in[16];
  const float* b1    = (const float*)d_in[17];
  const float* W2    = (const float*)d_in[18];
  const float* b2    = (const float*)d_in[19];
  const float* ln2s  = (const float*)d_in[20];
  const float* ln2b  = (const float*)d_in[21];
  const float* Wfc   = (const float*)d_in[22];
  const float* bfc   = (const float*)d_in[23];

  char* ws = (char*)d_ws;
  size_t off = 0;
  auto alloc = [&](size_t bytes) -> void* {
    void* p = ws + off;
    off += (bytes + 255) & ~(size_t)255;
    return p;
  };
  u16* xb     = (u16*)alloc((size_t)M_ROWS * H_DIM * 2);   // residual stream (post-LN)
  u16* projb  = (u16*)alloc((size_t)M_ROWS * H_DIM * 2);
  u16* big    = (u16*)alloc((size_t)M_ROWS * FF_DIM * 2);  // qkv / ff1 time-share
  u16* attno  = (u16*)alloc((size_t)M_ROWS * H_DIM * 2);
  u16* wqkvT  = (u16*)alloc((size_t)2 * QKV_LD * H_DIM * 2);
  u16* woT    = (u16*)alloc((size_t)2 * H_DIM * H_DIM * 2);
  u16* w1T    = (u16*)alloc((size_t)2 * FF_DIM * H_DIM * 2);
  u16* w2T    = (u16*)alloc((size_t)2 * H_DIM * FF_DIM * 2);
  u16* wfcT   = (u16*)alloc((size_t)OUT_DIM * H_DIM * 2);
  float* bqkv = (float*)alloc(2 * QKV_LD * 4);
  float* gsc  = (float*)alloc((size_t)BATCH * N_HEADS * L_SEQ * 4);
  float* gpm  = (float*)alloc((size_t)BATCH * N_HEADS * NSEG * 4);
  float* gps  = (float*)alloc((size_t)BATCH * N_HEADS * NSEG * 4);
  float* gpo  = (float*)alloc((size_t)BATCH * N_HEADS * NSEG * 4 * D_HEAD * 4);

  u16* qkvb = big;
  u16* ff1  = big;

  prep_weights<<<14130, 256, 0, stream>>>(Wq, Wk, Wv, Wo, W1, W2, Wfc,
                                          bq, bk, bv,
                                          wqkvT, woT, w1T, w2T, wfcT, bqkv);
  embed_ln_kernel<<<M_ROWS, 256, 0, stream>>>(ids, wemb, pemb, elns, elnb, xb);

  for (int l = 0; l < 2; l++) {
    gemm_s<1, 0, 0><<<(M_ROWS / 128) * (QKV_LD / 128), 256, 0, stream>>>(
        xb, wqkvT + (size_t)l * QKV_LD * H_DIM, bqkv + l * QKV_LD,
        nullptr, qkvb, nullptr, QKV_LD, H_DIM);
    attn_local_kernel<<<BATCH * N_HEADS * N_CHUNK, 512, 0, stream>>>(qkvb, amask, attno);
    attn_g_score<<<dim3(NSEG, BATCH * N_HEADS), 256, 0, stream>>>(qkvb, amask, gsc, gpm);
    attn_g_pv<<<dim3(NSEG, BATCH * N_HEADS), 256, 0, stream>>>(qkvb, gsc, gpm, gps, gpo);
    attn_g_combine<<<BATCH * N_HEADS, 64, 0, stream>>>(gps, gpo, attno);
    gemm_s<1, 0, 0><<<(M_ROWS / 128) * (H_DIM / 128), 256, 0, stream>>>(
        attno, woT + (size_t)l * H_DIM * H_DIM, bo + l * H_DIM,
        nullptr, projb, nullptr, H_DIM, H_DIM);
    add_ln_kernel<<<M_ROWS, 256, 0, stream>>>(xb, projb, ln1s + l * H_DIM, ln1b + l * H_DIM);
    gemm_s<1, 1, 0><<<(M_ROWS / 128) * (FF_DIM / 128), 256, 0, stream>>>(
        xb, w1T + (size_t)l * FF_DIM * H_DIM, b1 + l * FF_DIM,
        nullptr, ff1, nullptr, FF_DIM, H_DIM);
    gemm_s<1, 0, 0><<<(M_ROWS / 128) * (H_DIM / 128), 256, 0, stream>>>(
        ff1, w2T + (size_t)l * H_DIM * FF_DIM, b2 + l * H_DIM,
        nullptr, projb, nullptr, H_DIM, FF_DIM);
    add_ln_kernel<<<M_ROWS, 256, 0, stream>>>(xb, projb, ln2s + l * H_DIM, ln2b + l * H_DIM);
  }

  float* vdn = (float*)d_out;
  float* cls = vdn + (size_t)BATCH * L_SEQ * OUT_DIM;
  gemm_s<0, 0, 1><<<(M_ROWS / 128) * (OUT_DIM / 128), 256, 0, stream>>>(
      xb, wfcT, bfc, vdn, nullptr, cls, OUT_DIM, H_DIM);
}

// Round 17
// 555.740 us; speedup vs baseline: 1.0648x; 1.0025x over previous
//
#include <hip/hip_runtime.h>
#include <hip/hip_bf16.h>
#include <stdint.h>

#define L_SEQ 4096
#define H_DIM 768
#define N_HEADS 12
#define D_HEAD 64
#define N_CHUNK 32
#define CHUNK 128
#define FF_DIM 3072
#define OUT_DIM 384
#define BATCH 2
#define EPS_LN 1e-5f
#define M_ROWS (BATCH * L_SEQ)   /* 8192 */
#define QKV_LD (3 * H_DIM)       /* 2304 */
#define NGSEG 8                   /* global-row segments of 512 keys */

typedef unsigned short u16;
typedef __bf16 bx8 __attribute__((ext_vector_type(8)));
typedef float fx4 __attribute__((ext_vector_type(4)));
typedef u16 ux8 __attribute__((ext_vector_type(8)));

__device__ __forceinline__ u16 f2bf(float f) {
  union { float f; unsigned u; } x; x.f = f;
  unsigned r = x.u + 0x7fffu + ((x.u >> 16) & 1u);
  return (u16)(r >> 16);
}
__device__ __forceinline__ float bf2f(u16 v) {
  union { unsigned u; float f; } x; x.u = ((unsigned)v) << 16;
  return x.f;
}

__device__ __forceinline__ void gload16(const void* g, void* l) {
  __builtin_amdgcn_global_load_lds((const __attribute__((address_space(1))) void*)g,
                                   (__attribute__((address_space(3))) void*)l, 16, 0, 0);
}

// =====================================================================
// TLP GEMM (r6/r16 best): 128x128 tile, BK=64, 4 waves (2x2),
// single-buffered 32 KiB LDS, 2 barriers per K-step, launch_bounds(256,4).
// =====================================================================
template<int OUT_BF16, int DO_GELU, int DO_CLS>
__global__ __launch_bounds__(256, 4)
void gemm_s(const u16* __restrict__ A, const u16* __restrict__ Bt,
            const float* __restrict__ bias,
            float* __restrict__ Cf, u16* __restrict__ Cb,
            float* __restrict__ cls,
            int N, int K)
{
  __shared__ __align__(16) u16 As[128 * 64];
  __shared__ __align__(16) u16 Bs[128 * 64];
  const int tid = threadIdx.x;
  const int lane = tid & 63, w = tid >> 6;
  const int c16 = lane & 15, g = lane >> 4;
  const int wr = w >> 1, wc = w & 1;

  const int nbn = N >> 7;
  int id = blockIdx.x;
  id = (id & 7) * (gridDim.x >> 3) + (id >> 3);   // XCD swizzle (grids %8==0)
  const int bm = id / nbn, bn = id % nbn;

  const int srow = w * 8 + (lane >> 3);
  const int schunk = (lane & 7) ^ (lane >> 3);
  const u16* sA = A + (size_t)(bm * 128 + srow) * K + schunk * 8;
  const u16* sB = Bt + (size_t)(bn * 128 + srow) * K + schunk * 8;
  const int wdst = w * 512;

  fx4 acc[4][4] = {};

  for (int k0 = 0; k0 < K; k0 += 64) {
    #pragma unroll
    for (int i = 0; i < 4; i++) {
      gload16(sA + (size_t)(i * 32) * K + k0, &As[i * 2048 + wdst]);
      gload16(sB + (size_t)(i * 32) * K + k0, &Bs[i * 2048 + wdst]);
    }
    __syncthreads();
    #pragma unroll
    for (int h = 0; h < 2; h++) {
      bx8 af[4], bf[4];
      #pragma unroll
      for (int m = 0; m < 4; m++) {
        const int row = wr * 64 + m * 16 + c16;
        af[m] = *(const bx8*)&As[row * 64 + (((h << 2) + g) ^ (c16 & 7)) * 8];
      }
      #pragma unroll
      for (int n = 0; n < 4; n++) {
        const int row = wc * 64 + n * 16 + c16;
        bf[n] = *(const bx8*)&Bs[row * 64 + (((h << 2) + g) ^ (c16 & 7)) * 8];
      }
      #pragma unroll
      for (int m = 0; m < 4; m++)
        #pragma unroll
        for (int n = 0; n < 4; n++)
          acc[m][n] = __builtin_amdgcn_mfma_f32_16x16x32_bf16(af[m], bf[n], acc[m][n], 0, 0, 0);
    }
    __syncthreads();
  }

  const int row0 = bm * 128 + wr * 64 + g * 4;
  const int col0 = bn * 128 + wc * 64 + c16;
  #pragma unroll
  for (int n = 0; n < 4; n++) {
    const int col = col0 + n * 16;
    const float bb = bias[col];
    #pragma unroll
    for (int m = 0; m < 4; m++) {
      #pragma unroll
      for (int r = 0; r < 4; r++) {
        float y = acc[m][n][r] + bb;
        if (DO_GELU) {
          const float tt = y;
          y = 0.5f * tt * (1.0f + tanhf(0.7978845608f * (tt + 0.044715f * tt * tt * tt)));
        }
        const int row = row0 + m * 16 + r;
        const size_t idx = (size_t)row * N + col;
        if (OUT_BF16) Cb[idx] = f2bf(y);
        else Cf[idx] = y;
        if (DO_CLS) {
          if ((row & (L_SEQ - 1)) == 0)
            cls[(row >> 12) * OUT_DIM + col] = y;
        }
      }
    }
  }
}

// =====================================================================
// Local (windowed) attention v7 (r14 best): streamed KV tiles + T14
// issue-early / write-late + double-buffered K,V + 1 barrier/tile +
// setprio. LDS 48 KB, 2 blocks/CU, no spill.
// =====================================================================
#define P2_STR 64   /* u16 row stride of per-wave P tile (64 keys) */

__global__ __launch_bounds__(512, 2)
void attn_local_kernel(const u16* __restrict__ qkv, const int* __restrict__ amask,
                       u16* __restrict__ attnout)
{
  __shared__ __align__(16) u16 Klds[2][64 * 64];       // K [key][d], swizzled
  __shared__ __align__(16) u16 Vlds[2][64 * 64];       // V^T [d][key], swizzled
  __shared__ __align__(16) u16 Plds[8 * 16 * P2_STR];  // per-wave P

  const int tid = threadIdx.x;
  const int lane = tid & 63, w = tid >> 6;
  const int c16 = lane & 15, g = lane >> 4;

  const int bh = blockIdx.x >> 5;
  const int n = blockIdx.x & 31;
  const int b = bh / N_HEADS, h = bh % N_HEADS;

  const u16* qkvb = qkv + (size_t)b * L_SEQ * QKV_LD + h * D_HEAD;
  const int chunk_lo = n * CHUNK - CHUNK;

  const int qrow = n * CHUNK + w * 16 + c16;
  const u16* qp = qkvb + (size_t)qrow * QKV_LD + g * 8;
  const bx8 aq0 = *(const bx8*)qp;
  const bx8 aq1 = *(const bx8*)(qp + 32);

  unsigned kvm = 0;
  #pragma unroll
  for (int kf = 0; kf < 24; kf++) {
    const int pos = chunk_lo + kf * 16 + c16;
    bool ok = (pos >= 1) && (pos < L_SEQ);
    if (ok) ok = (amask[b * L_SEQ + pos] > 0);
    kvm |= ((unsigned)ok) << kf;
  }

  const int cq = w * 16 + g * 4;

  float m[4], l[4], pgv[4];
  {
    const u16* kp = qkvb + H_DIM + g * 8;   // pos 0
    const bx8 b0 = *(const bx8*)kp;
    const bx8 b1 = *(const bx8*)(kp + 32);
    fx4 sg = {};
    sg = __builtin_amdgcn_mfma_f32_16x16x32_bf16(aq0, b0, sg, 0, 0, 0);
    sg = __builtin_amdgcn_mfma_f32_16x16x32_bf16(aq1, b1, sg, 0, 0, 0);
    #pragma unroll
    for (int r = 0; r < 4; r++) {
      const float val = (c16 == 0) ? sg[r] * 0.125f : -1.0e9f;
      float mm = val;
      mm = fmaxf(mm, __shfl_xor(mm, 1));
      mm = fmaxf(mm, __shfl_xor(mm, 2));
      mm = fmaxf(mm, __shfl_xor(mm, 4));
      mm = fmaxf(mm, __shfl_xor(mm, 8));
      m[r] = mm;
      pgv[r] = __expf(val - mm);
      float t = pgv[r];
      t += __shfl_xor(t, 1);
      t += __shfl_xor(t, 2);
      t += __shfl_xor(t, 4);
      t += __shfl_xor(t, 8);
      l[r] = t;
    }
  }

  const int krow_s = w * 8 + (lane >> 3);
  const int ksc = (lane & 7) ^ (krow_s & 7);      // pre-swizzled K src chunk
  const int d = lane;                              // V staging: lane = d
  const int vdst = d * 64 + ((w ^ (d & 7)) << 3);  // V^T write pos (swizzled)

  {
    int pos = chunk_lo + krow_s;
    if (pos < 0) pos = 0;
    if (pos >= L_SEQ) pos = L_SEQ - 1;
    gload16(qkvb + (size_t)pos * QKV_LD + H_DIM + ksc * 8, &Klds[0][w * 512]);
  }
  ux8 vreg;
  #pragma unroll
  for (int j = 0; j < 8; j++) {
    int pos = chunk_lo + w * 8 + j;
    if (pos < 0) pos = 0;
    if (pos >= L_SEQ) pos = L_SEQ - 1;
    vreg[j] = qkvb[(size_t)pos * QKV_LD + 2 * H_DIM + d];
  }
  *(ux8*)&Vlds[0][vdst] = vreg;
  __syncthreads();   // K(0) drained; V(0) visible

  fx4 o[4] = {};
  u16* pb = Plds + w * 16 * P2_STR;
  const int prow = (w * 16 + c16) * P2_STR;

  for (int t = 0; t < 6; t++) {
    const int cur = t & 1, nxt = cur ^ 1;

    if (t < 5) {
      int pos = chunk_lo + (t + 1) * 64 + krow_s;
      if (pos < 0) pos = 0;
      if (pos >= L_SEQ) pos = L_SEQ - 1;
      gload16(qkvb + (size_t)pos * QKV_LD + H_DIM + ksc * 8, &Klds[nxt][w * 512]);
      #pragma unroll
      for (int j = 0; j < 8; j++) {
        int vp = chunk_lo + (t + 1) * 64 + w * 8 + j;
        if (vp < 0) vp = 0;
        if (vp >= L_SEQ) vp = L_SEQ - 1;
        vreg[j] = qkvb[(size_t)vp * QKV_LD + 2 * H_DIM + d];
      }
    }

    fx4 s[4];
    __builtin_amdgcn_s_setprio(1);
    #pragma unroll
    for (int kf = 0; kf < 4; kf++) {
      const int krow = kf * 16 + c16;                 // krow&7 == c16&7
      const bx8 b0 = *(const bx8*)&Klds[cur][krow * 64 + ((g ^ (c16 & 7)) << 3)];
      const bx8 b1 = *(const bx8*)&Klds[cur][krow * 64 + (((4 + g) ^ (c16 & 7)) << 3)];
      fx4 a = {};
      a = __builtin_amdgcn_mfma_f32_16x16x32_bf16(aq0, b0, a, 0, 0, 0);
      a = __builtin_amdgcn_mfma_f32_16x16x32_bf16(aq1, b1, a, 0, 0, 0);
      s[kf] = a;
    }
    __builtin_amdgcn_s_setprio(0);
    float pmax[4];
    #pragma unroll
    for (int r = 0; r < 4; r++) pmax[r] = -3.0e38f;
    #pragma unroll
    for (int kf = 0; kf < 4; kf++) {
      const int KF = t * 4 + kf;
      const int j = KF * 16 + c16;
      const bool kv = ((kvm >> KF) & 1u) != 0;
      #pragma unroll
      for (int r = 0; r < 4; r++) {
        const int c = cq + r;
        const bool keep = kv && (j >= c && j <= c + 256);
        const float val = keep ? s[kf][r] * 0.125f : -1.0e9f;
        s[kf][r] = val;
        pmax[r] = fmaxf(pmax[r], val);
      }
    }
    #pragma unroll
    for (int r = 0; r < 4; r++) {
      float mm = pmax[r];
      mm = fmaxf(mm, __shfl_xor(mm, 1));
      mm = fmaxf(mm, __shfl_xor(mm, 2));
      mm = fmaxf(mm, __shfl_xor(mm, 4));
      mm = fmaxf(mm, __shfl_xor(mm, 8));
      const float newm = fmaxf(m[r], mm);
      const float scale = __expf(m[r] - newm);
      m[r] = newm;
      l[r] *= scale;
      pgv[r] *= scale;
      #pragma unroll
      for (int df = 0; df < 4; df++) o[df][r] *= scale;
    }
    float lsum[4] = {0.f, 0.f, 0.f, 0.f};
    #pragma unroll
    for (int kf = 0; kf < 4; kf++)
      #pragma unroll
      for (int r = 0; r < 4; r++) {
        const float p = __expf(s[kf][r] - m[r]);
        s[kf][r] = p;
        lsum[r] += p;
      }
    #pragma unroll
    for (int r = 0; r < 4; r++) {
      float tt = lsum[r];
      tt += __shfl_xor(tt, 1);
      tt += __shfl_xor(tt, 2);
      tt += __shfl_xor(tt, 4);
      tt += __shfl_xor(tt, 8);
      l[r] += tt;
    }
    #pragma unroll
    for (int kf = 0; kf < 4; kf++) {
      #pragma unroll
      for (int r = 0; r < 4; r++) {
        const int rr = g * 4 + r;
        const int jj = kf * 16 + c16;       // 0..63 within tile
        pb[rr * P2_STR + (((jj >> 3) ^ (rr & 7)) << 3) + (jj & 7)] = f2bf(s[kf][r]);
      }
    }
    __builtin_amdgcn_s_setprio(1);
    #pragma unroll
    for (int kt = 0; kt < 2; kt++) {
      const int ckp = kt * 4 + g;           // chunk 0..7
      const bx8 pa = *(const bx8*)&Plds[prow + ((ckp ^ (c16 & 7)) << 3)];
      #pragma unroll
      for (int df = 0; df < 4; df++) {
        const int vrow = df * 16 + c16;
        const bx8 vvf = *(const bx8*)&Vlds[cur][vrow * 64 + ((ckp ^ (c16 & 7)) << 3)];
        o[df] = __builtin_amdgcn_mfma_f32_16x16x32_bf16(pa, vvf, o[df], 0, 0, 0);
      }
    }
    __builtin_amdgcn_s_setprio(0);
    if (t < 5) *(ux8*)&Vlds[nxt][vdst] = vreg;
    __syncthreads();
  }

  float rinv[4], pg[4];
  #pragma unroll
  for (int r = 0; r < 4; r++) {
    rinv[r] = 1.0f / l[r];
    pg[r] = __shfl(pgv[r], g * 16);
  }
  u16* ob = attnout + (size_t)b * L_SEQ * H_DIM + h * D_HEAD;
  const int posq = n * CHUNK + w * 16 + g * 4;
  #pragma unroll
  for (int df = 0; df < 4; df++) {
    const float v0f = bf2f(qkvb[2 * H_DIM + df * 16 + c16]);
    #pragma unroll
    for (int r = 0; r < 4; r++)
      ob[(size_t)(posq + r) * H_DIM + df * 16 + c16] =
          f2bf((o[df][r] + pg[r] * v0f) * rinv[r]);
  }
}

// =====================================================================
// Global row (query 0): ONE split-flash kernel (was score+pv), 192
// blocks = 24 heads x 8 segments of 512 keys. Math identical to the
// r15-validated branch; standalone dispatch keeps the light footprint.
// =====================================================================
__global__ __launch_bounds__(512)
void attn_g_split(const u16* __restrict__ qkv, const int* __restrict__ amask,
                  float* __restrict__ gpm, float* __restrict__ gps,
                  float* __restrict__ gpo)
{
  __shared__ float qs[D_HEAD];
  __shared__ float es[512];
  __shared__ float red[8];
  const int tid = threadIdx.x;
  const int lane = tid & 63, w = tid >> 6;
  const int idx = blockIdx.x;
  const int bh = idx >> 3, seg = idx & 7;
  const int b = bh / N_HEADS, h = bh % N_HEADS;
  const u16* base = qkv + (size_t)b * L_SEQ * QKV_LD + h * D_HEAD;

  if (tid < D_HEAD) qs[tid] = bf2f(base[tid]);
  __syncthreads();

  const int key = seg * 512 + tid;
  const ux8* kp = (const ux8*)(base + (size_t)key * QKV_LD + H_DIM);
  float dot = 0.f;
  #pragma unroll
  for (int i = 0; i < 8; i++) {
    const ux8 kv = kp[i];
    #pragma unroll
    for (int j = 0; j < 8; j++) dot += qs[i * 8 + j] * bf2f(kv[j]);
  }
  float sv = dot * 0.125f;
  if (amask[b * L_SEQ + key] == 0) sv = -1.0e9f;

  float mv = sv;
  #pragma unroll
  for (int off = 32; off > 0; off >>= 1) mv = fmaxf(mv, __shfl_xor(mv, off));
  if (lane == 0) red[w] = mv;
  __syncthreads();
  float M = -3.0e38f;
  #pragma unroll
  for (int i = 0; i < 8; i++) M = fmaxf(M, red[i]);

  const float e = __expf(sv - M);
  es[tid] = e;
  float s = e;
  #pragma unroll
  for (int off = 32; off > 0; off >>= 1) s += __shfl_xor(s, off);
  __syncthreads();            // red reads (max) + es writes done
  if (lane == 0) red[w] = s;
  __syncthreads();
  float Sl = 0.f;
  #pragma unroll
  for (int i = 0; i < 8; i++) Sl += red[i];

  const int gi = tid >> 6, d = lane;
  const u16* vb = base + 2 * H_DIM + d;
  float acc = 0.f;
  #pragma unroll 4
  for (int i = 0; i < 64; i++) {
    const int kk = seg * 512 + gi * 64 + i;
    acc += es[gi * 64 + i] * bf2f(vb[(size_t)kk * QKV_LD]);
  }
  gpo[(((size_t)bh * NGSEG + seg) * 8 + gi) * D_HEAD + d] = acc;
  if (tid == 0) { gpm[bh * NGSEG + seg] = M; gps[bh * NGSEG + seg] = Sl; }
}

// combine split-flash partials -> query row 0 (r15-verified rescale)
__global__ __launch_bounds__(64)
void attn_g_combine(const float* __restrict__ gpm, const float* __restrict__ gps,
                    const float* __restrict__ gpo, u16* __restrict__ attnout)
{
  const int bh = blockIdx.x;
  const int b = bh / N_HEADS, h = bh % N_HEADS;
  const int d = threadIdx.x;
  float M = -3.0e38f;
  #pragma unroll
  for (int s = 0; s < NGSEG; s++) M = fmaxf(M, gpm[bh * NGSEG + s]);
  float S = 0.f, acc = 0.f;
  #pragma unroll
  for (int s = 0; s < NGSEG; s++) {
    const float sc = __expf(gpm[bh * NGSEG + s] - M);
    S += gps[bh * NGSEG + s] * sc;
    #pragma unroll
    for (int gi = 0; gi < 8; gi++)
      acc += gpo[(((size_t)bh * NGSEG + s) * 8 + gi) * D_HEAD + d] * sc;
  }
  attnout[(size_t)b * L_SEQ * H_DIM + h * D_HEAD + d] = f2bf(acc / S);
}

// ---------------- LayerNorm kernels (bf16 residual stream) ----------------
__device__ __forceinline__ void block_stats(float sum, float sq, float* red,
                                            float& mean, float& rstd)
{
  const int lane = threadIdx.x & 63, wv = threadIdx.x >> 6;
  #pragma unroll
  for (int off = 32; off > 0; off >>= 1) {
    sum += __shfl_xor(sum, off);
    sq  += __shfl_xor(sq, off);
  }
  if (lane == 0) { red[wv] = sum; red[4 + wv] = sq; }
  __syncthreads();
  sum = red[0] + red[1] + red[2] + red[3];
  sq  = red[4] + red[5] + red[6] + red[7];
  mean = sum * (1.0f / H_DIM);
  const float var = sq * (1.0f / H_DIM) - mean * mean;
  rstd = rsqrtf(var + EPS_LN);
}

__global__ __launch_bounds__(256)
void embed_ln_kernel(const int* __restrict__ ids, const float* __restrict__ wemb,
                     const float* __restrict__ pemb, const float* __restrict__ gam,
                     const float* __restrict__ bet, u16* __restrict__ xb)
{
  __shared__ float red[8];
  const int row = blockIdx.x, tid = threadIdx.x;
  const int l = row & (L_SEQ - 1);
  const int id = ids[row];
  float v[3]; float sum = 0.f, sq = 0.f;
  #pragma unroll
  for (int i = 0; i < 3; i++) {
    const int c = tid + i * 256;
    const float t = wemb[(size_t)id * H_DIM + c] + pemb[(size_t)l * H_DIM + c];
    v[i] = t; sum += t; sq += t * t;
  }
  float mean, rstd;
  block_stats(sum, sq, red, mean, rstd);
  #pragma unroll
  for (int i = 0; i < 3; i++) {
    const int c = tid + i * 256;
    const float y = (v[i] - mean) * rstd * gam[c] + bet[c];
    xb[(size_t)row * H_DIM + c] = f2bf(y);
  }
}

__global__ __launch_bounds__(256)
void add_ln_kernel(u16* xio, const u16* __restrict__ yin,
                   const float* __restrict__ gam, const float* __restrict__ bet)
{
  __shared__ float red[8];
  const int row = blockIdx.x, tid = threadIdx.x;
  float v[3]; float sum = 0.f, sq = 0.f;
  #pragma unroll
  for (int i = 0; i < 3; i++) {
    const int c = tid + i * 256;
    const float t = bf2f(xio[(size_t)row * H_DIM + c]) + bf2f(yin[(size_t)row * H_DIM + c]);
    v[i] = t; sum += t; sq += t * t;
  }
  float mean, rstd;
  block_stats(sum, sq, red, mean, rstd);
  #pragma unroll
  for (int i = 0; i < 3; i++) {
    const int c = tid + i * 256;
    const float y = (v[i] - mean) * rstd * gam[c] + bet[c];
    xio[(size_t)row * H_DIM + c] = f2bf(y);
  }
}

// ---------------- Fused weight prep ----------------
__global__ __launch_bounds__(256)
void prep_weights(const float* __restrict__ Wq, const float* __restrict__ Wk,
                  const float* __restrict__ Wv, const float* __restrict__ Wo,
                  const float* __restrict__ W1, const float* __restrict__ W2,
                  const float* __restrict__ Wfc,
                  const float* __restrict__ bq, const float* __restrict__ bk,
                  const float* __restrict__ bv,
                  u16* __restrict__ wqkvT, u16* __restrict__ woT,
                  u16* __restrict__ w1T, u16* __restrict__ w2T,
                  u16* __restrict__ wfcT, float* __restrict__ bqkv)
{
  const int t = blockIdx.x;
  const int tid = threadIdx.x;
  if (t >= 14112) {   // bias concat: 18 blocks
    const int idx = t - 14112;
    const int l = idx / 9, j = idx % 9;
    const int i = j * 256 + tid;
    if (i < H_DIM)          bqkv[l * QKV_LD + i] = bq[l * H_DIM + i];
    else if (i < 2 * H_DIM) bqkv[l * QKV_LD + i] = bk[l * H_DIM + i - H_DIM];
    else if (i < 3 * H_DIM) bqkv[l * QKV_LD + i] = bv[l * H_DIM + i - 2 * H_DIM];
    return;
  }
  const float* src; u16* dst; int K, N, r;
  if (t < 13824) {
    const int l = t / 6912; r = t % 6912;
    if (r < 2304) {
      const int m = r / 576; r = r % 576; K = H_DIM; N = H_DIM;
      if (m == 0)      src = Wq + (size_t)l * H_DIM * H_DIM;
      else if (m == 1) src = Wk + (size_t)l * H_DIM * H_DIM;
      else if (m == 2) src = Wv + (size_t)l * H_DIM * H_DIM;
      else             src = Wo + (size_t)l * H_DIM * H_DIM;
      dst = (m < 3) ? wqkvT + (size_t)l * QKV_LD * H_DIM + (size_t)m * H_DIM * H_DIM
                    : woT + (size_t)l * H_DIM * H_DIM;
    } else if (r < 4608) {
      r -= 2304; K = H_DIM; N = FF_DIM;
      src = W1 + (size_t)l * H_DIM * FF_DIM;
      dst = w1T + (size_t)l * FF_DIM * H_DIM;
    } else {
      r -= 4608; K = FF_DIM; N = H_DIM;
      src = W2 + (size_t)l * FF_DIM * H_DIM;
      dst = w2T + (size_t)l * H_DIM * FF_DIM;
    }
  } else {
    r = t - 13824; K = H_DIM; N = OUT_DIM; src = Wfc; dst = wfcT;
  }
  const int ntn = N >> 5;
  const int k0 = (r / ntn) * 32, n0 = (r % ntn) * 32;
  __shared__ float tile[32][33];
  const int tx = tid & 31, ty = tid >> 5;
  #pragma unroll
  for (int i = 0; i < 32; i += 8)
    tile[ty + i][tx] = src[(size_t)(k0 + ty + i) * N + n0 + tx];
  __syncthreads();
  #pragma unroll
  for (int i = 0; i < 32; i += 8)
    dst[(size_t)(n0 + ty + i) * K + k0 + tx] = f2bf(tile[tx][ty + i]);
}

// ---------------- host ----------------
extern "C" void kernel_launch(void* const* d_in, const int* in_sizes, int n_in,
                              void* d_out, int out_size, void* d_ws, size_t ws_size,
                              hipStream_t stream)
{
  (void)in_sizes; (void)n_in; (void)out_size; (void)ws_size;
  const int*   ids   = (const int*)d_in[0];
  const int*   amask = (const int*)d_in[1];
  const float* wemb  = (const float*)d_in[2];
  const float* pemb  = (const float*)d_in[3];
  const float* elns  = (const float*)d_in[4];
  const float* elnb  = (const float*)d_in[5];
  const float* Wq    = (const float*)d_in[6];
  const float* bq    = (const float*)d_in[7];
  const float* Wk    = (const float*)d_in[8];
  const float* bk    = (const float*)d_in[9];
  const float* Wv    = (const float*)d_in[10];
  const float* bv    = (const float*)d_in[11];
  const float* Wo    = (const float*)d_in[12];
  const float* bo    = (const float*)d_in[13];
  const float* ln1s  = (const float*)d_in[14];
  const float* ln1b  = (const float*)d_in[15];
  const float* W1    = (const float*)d_in[16];
  const float* b1    = (const float*)d_in[17];
  const float* W2    = (const float*)d_in[18];
  const float* b2    = (const float*)d_in[19];
  const float* ln2s  = (const float*)d_in[20];
  const float* ln2b  = (const float*)d_in[21];
  const float* Wfc   = (const float*)d_in[22];
  const float* bfc   = (const float*)d_in[23];

  char* ws = (char*)d_ws;
  size_t off = 0;
  auto alloc = [&](size_t bytes) -> void* {
    void* p = ws + off;
    off += (bytes + 255) & ~(size_t)255;
    return p;
  };
  u16* xb     = (u16*)alloc((size_t)M_ROWS * H_DIM * 2);   // residual stream (post-LN)
  u16* projb  = (u16*)alloc((size_t)M_ROWS * H_DIM * 2);
  u16* big    = (u16*)alloc((size_t)M_ROWS * FF_DIM * 2);  // qkv / ff1 time-share
  u16* attno  = (u16*)alloc((size_t)M_ROWS * H_DIM * 2);
  u16* wqkvT  = (u16*)alloc((size_t)2 * QKV_LD * H_DIM * 2);
  u16* woT    = (u16*)alloc((size_t)2 * H_DIM * H_DIM * 2);
  u16* w1T    = (u16*)alloc((size_t)2 * FF_DIM * H_DIM * 2);
  u16* w2T    = (u16*)alloc((size_t)2 * H_DIM * FF_DIM * 2);
  u16* wfcT   = (u16*)alloc((size_t)OUT_DIM * H_DIM * 2);
  float* bqkv = (float*)alloc(2 * QKV_LD * 4);
  float* gpm  = (float*)alloc((size_t)BATCH * N_HEADS * NGSEG * 4);
  float* gps  = (float*)alloc((size_t)BATCH * N_HEADS * NGSEG * 4);
  float* gpo  = (float*)alloc((size_t)BATCH * N_HEADS * NGSEG * 8 * D_HEAD * 4);

  u16* qkvb = big;
  u16* ff1  = big;

  prep_weights<<<14130, 256, 0, stream>>>(Wq, Wk, Wv, Wo, W1, W2, Wfc,
                                          bq, bk, bv,
                                          wqkvT, woT, w1T, w2T, wfcT, bqkv);
  embed_ln_kernel<<<M_ROWS, 256, 0, stream>>>(ids, wemb, pemb, elns, elnb, xb);

  for (int l = 0; l < 2; l++) {
    gemm_s<1, 0, 0><<<(M_ROWS / 128) * (QKV_LD / 128), 256, 0, stream>>>(
        xb, wqkvT + (size_t)l * QKV_LD * H_DIM, bqkv + l * QKV_LD,
        nullptr, qkvb, nullptr, QKV_LD, H_DIM);
    attn_local_kernel<<<BATCH * N_HEADS * N_CHUNK, 512, 0, stream>>>(qkvb, amask, attno);
    attn_g_split<<<BATCH * N_HEADS * NGSEG, 512, 0, stream>>>(qkvb, amask, gpm, gps, gpo);
    attn_g_combine<<<BATCH * N_HEADS, 64, 0, stream>>>(gpm, gps, gpo, attno);
    gemm_s<1, 0, 0><<<(M_ROWS / 128) * (H_DIM / 128), 256, 0, stream>>>(
        attno, woT + (size_t)l * H_DIM * H_DIM, bo + l * H_DIM,
        nullptr, projb, nullptr, H_DIM, H_DIM);
    add_ln_kernel<<<M_ROWS, 256, 0, stream>>>(xb, projb, ln1s + l * H_DIM, ln1b + l * H_DIM);
    gemm_s<1, 1, 0><<<(M_ROWS / 128) * (FF_DIM / 128), 256, 0, stream>>>(
        xb, w1T + (size_t)l * FF_DIM * H_DIM, b1 + l * FF_DIM,
        nullptr, ff1, nullptr, FF_DIM, H_DIM);
    gemm_s<1, 0, 0><<<(M_ROWS / 128) * (H_DIM / 128), 256, 0, stream>>>(
        ff1, w2T + (size_t)l * H_DIM * FF_DIM, b2 + l * H_DIM,
        nullptr, projb, nullptr, H_DIM, FF_DIM);
    add_ln_kernel<<<M_ROWS, 256, 0, stream>>>(xb, projb, ln2s + l * H_DIM, ln2b + l * H_DIM);
  }

  float* vdn = (float*)d_out;
  float* cls = vdn + (size_t)BATCH * L_SEQ * OUT_DIM;
  gemm_s<0, 0, 1><<<(M_ROWS / 128) * (OUT_DIM / 128), 256, 0, stream>>>(
      xb, wfcT, bfc, vdn, nullptr, cls, OUT_DIM, H_DIM);
}

// Round 18
// 547.004 us; speedup vs baseline: 1.0818x; 1.0160x over previous
//
#include <hip/hip_runtime.h>
#include <hip/hip_bf16.h>
#include <stdint.h>

#define L_SEQ 4096
#define H_DIM 768
#define N_HEADS 12
#define D_HEAD 64
#define N_CHUNK 32
#define CHUNK 128
#define FF_DIM 3072
#define OUT_DIM 384
#define BATCH 2
#define EPS_LN 1e-5f
#define M_ROWS (BATCH * L_SEQ)   /* 8192 */
#define QKV_LD (3 * H_DIM)       /* 2304 */
#define NGSEG 8                   /* global-row segments of 512 keys */

typedef unsigned short u16;
typedef __bf16 bx8 __attribute__((ext_vector_type(8)));
typedef float fx4 __attribute__((ext_vector_type(4)));
typedef u16 ux8 __attribute__((ext_vector_type(8)));
typedef u16 ux4 __attribute__((ext_vector_type(4)));

__device__ __forceinline__ u16 f2bf(float f) {
  union { float f; unsigned u; } x; x.f = f;
  unsigned r = x.u + 0x7fffu + ((x.u >> 16) & 1u);
  return (u16)(r >> 16);
}
__device__ __forceinline__ float bf2f(u16 v) {
  union { unsigned u; float f; } x; x.u = ((unsigned)v) << 16;
  return x.f;
}

__device__ __forceinline__ void gload16(const void* g, void* l) {
  __builtin_amdgcn_global_load_lds((const __attribute__((address_space(1))) void*)g,
                                   (__attribute__((address_space(3))) void*)l, 16, 0, 0);
}

// fast tanh-GELU: tanh(a) = (e^{2a}-1)/(e^{2a}+1), a clamped to +-10
// (tanh saturated beyond; avoids exp overflow). |err| ~1e-6.
__device__ __forceinline__ float gelu_f(float y) {
  float a = 0.7978845608f * (y + 0.044715f * y * y * y);
  a = fminf(fmaxf(a, -10.f), 10.f);
  const float e = __expf(2.0f * a);
  return 0.5f * y * (1.0f + (e - 1.0f) / (e + 1.0f));
}

// =====================================================================
// TLP GEMM (r6/r16 best): 128x128 tile, BK=64, 4 waves (2x2),
// single-buffered 32 KiB LDS, 2 barriers per K-step, launch_bounds(256,4).
// =====================================================================
template<int OUT_BF16, int DO_GELU, int DO_CLS>
__global__ __launch_bounds__(256, 4)
void gemm_s(const u16* __restrict__ A, const u16* __restrict__ Bt,
            const float* __restrict__ bias,
            float* __restrict__ Cf, u16* __restrict__ Cb,
            float* __restrict__ cls,
            int N, int K)
{
  __shared__ __align__(16) u16 As[128 * 64];
  __shared__ __align__(16) u16 Bs[128 * 64];
  const int tid = threadIdx.x;
  const int lane = tid & 63, w = tid >> 6;
  const int c16 = lane & 15, g = lane >> 4;
  const int wr = w >> 1, wc = w & 1;

  const int nbn = N >> 7;
  int id = blockIdx.x;
  id = (id & 7) * (gridDim.x >> 3) + (id >> 3);   // XCD swizzle (grids %8==0)
  const int bm = id / nbn, bn = id % nbn;

  const int srow = w * 8 + (lane >> 3);
  const int schunk = (lane & 7) ^ (lane >> 3);
  const u16* sA = A + (size_t)(bm * 128 + srow) * K + schunk * 8;
  const u16* sB = Bt + (size_t)(bn * 128 + srow) * K + schunk * 8;
  const int wdst = w * 512;

  fx4 acc[4][4] = {};

  for (int k0 = 0; k0 < K; k0 += 64) {
    #pragma unroll
    for (int i = 0; i < 4; i++) {
      gload16(sA + (size_t)(i * 32) * K + k0, &As[i * 2048 + wdst]);
      gload16(sB + (size_t)(i * 32) * K + k0, &Bs[i * 2048 + wdst]);
    }
    __syncthreads();
    #pragma unroll
    for (int h = 0; h < 2; h++) {
      bx8 af[4], bf[4];
      #pragma unroll
      for (int m = 0; m < 4; m++) {
        const int row = wr * 64 + m * 16 + c16;
        af[m] = *(const bx8*)&As[row * 64 + (((h << 2) + g) ^ (c16 & 7)) * 8];
      }
      #pragma unroll
      for (int n = 0; n < 4; n++) {
        const int row = wc * 64 + n * 16 + c16;
        bf[n] = *(const bx8*)&Bs[row * 64 + (((h << 2) + g) ^ (c16 & 7)) * 8];
      }
      #pragma unroll
      for (int m = 0; m < 4; m++)
        #pragma unroll
        for (int n = 0; n < 4; n++)
          acc[m][n] = __builtin_amdgcn_mfma_f32_16x16x32_bf16(af[m], bf[n], acc[m][n], 0, 0, 0);
    }
    __syncthreads();
  }

  const int row0 = bm * 128 + wr * 64 + g * 4;
  const int col0 = bn * 128 + wc * 64 + c16;
  #pragma unroll
  for (int n = 0; n < 4; n++) {
    const int col = col0 + n * 16;
    const float bb = bias[col];
    #pragma unroll
    for (int m = 0; m < 4; m++) {
      #pragma unroll
      for (int r = 0; r < 4; r++) {
        float y = acc[m][n][r] + bb;
        if (DO_GELU) y = gelu_f(y);
        const int row = row0 + m * 16 + r;
        const size_t idx = (size_t)row * N + col;
        if (OUT_BF16) Cb[idx] = f2bf(y);
        else Cf[idx] = y;
        if (DO_CLS) {
          if ((row & (L_SEQ - 1)) == 0)
            cls[(row >> 12) * OUT_DIM + col] = y;
        }
      }
    }
  }
}

// =====================================================================
// Local (windowed) attention v7 (r14 best): streamed KV tiles + T14
// issue-early / write-late + double-buffered K,V + 1 barrier/tile +
// setprio. LDS 48 KB, 2 blocks/CU, no spill.
// =====================================================================
#define P2_STR 64   /* u16 row stride of per-wave P tile (64 keys) */

__global__ __launch_bounds__(512, 2)
void attn_local_kernel(const u16* __restrict__ qkv, const int* __restrict__ amask,
                       u16* __restrict__ attnout)
{
  __shared__ __align__(16) u16 Klds[2][64 * 64];       // K [key][d], swizzled
  __shared__ __align__(16) u16 Vlds[2][64 * 64];       // V^T [d][key], swizzled
  __shared__ __align__(16) u16 Plds[8 * 16 * P2_STR];  // per-wave P

  const int tid = threadIdx.x;
  const int lane = tid & 63, w = tid >> 6;
  const int c16 = lane & 15, g = lane >> 4;

  const int bh = blockIdx.x >> 5;
  const int n = blockIdx.x & 31;
  const int b = bh / N_HEADS, h = bh % N_HEADS;

  const u16* qkvb = qkv + (size_t)b * L_SEQ * QKV_LD + h * D_HEAD;
  const int chunk_lo = n * CHUNK - CHUNK;

  const int qrow = n * CHUNK + w * 16 + c16;
  const u16* qp = qkvb + (size_t)qrow * QKV_LD + g * 8;
  const bx8 aq0 = *(const bx8*)qp;
  const bx8 aq1 = *(const bx8*)(qp + 32);

  unsigned kvm = 0;
  #pragma unroll
  for (int kf = 0; kf < 24; kf++) {
    const int pos = chunk_lo + kf * 16 + c16;
    bool ok = (pos >= 1) && (pos < L_SEQ);
    if (ok) ok = (amask[b * L_SEQ + pos] > 0);
    kvm |= ((unsigned)ok) << kf;
  }

  const int cq = w * 16 + g * 4;

  float m[4], l[4], pgv[4];
  {
    const u16* kp = qkvb + H_DIM + g * 8;   // pos 0
    const bx8 b0 = *(const bx8*)kp;
    const bx8 b1 = *(const bx8*)(kp + 32);
    fx4 sg = {};
    sg = __builtin_amdgcn_mfma_f32_16x16x32_bf16(aq0, b0, sg, 0, 0, 0);
    sg = __builtin_amdgcn_mfma_f32_16x16x32_bf16(aq1, b1, sg, 0, 0, 0);
    #pragma unroll
    for (int r = 0; r < 4; r++) {
      const float val = (c16 == 0) ? sg[r] * 0.125f : -1.0e9f;
      float mm = val;
      mm = fmaxf(mm, __shfl_xor(mm, 1));
      mm = fmaxf(mm, __shfl_xor(mm, 2));
      mm = fmaxf(mm, __shfl_xor(mm, 4));
      mm = fmaxf(mm, __shfl_xor(mm, 8));
      m[r] = mm;
      pgv[r] = __expf(val - mm);
      float t = pgv[r];
      t += __shfl_xor(t, 1);
      t += __shfl_xor(t, 2);
      t += __shfl_xor(t, 4);
      t += __shfl_xor(t, 8);
      l[r] = t;
    }
  }

  const int krow_s = w * 8 + (lane >> 3);
  const int ksc = (lane & 7) ^ (krow_s & 7);      // pre-swizzled K src chunk
  const int d = lane;                              // V staging: lane = d
  const int vdst = d * 64 + ((w ^ (d & 7)) << 3);  // V^T write pos (swizzled)

  {
    int pos = chunk_lo + krow_s;
    if (pos < 0) pos = 0;
    if (pos >= L_SEQ) pos = L_SEQ - 1;
    gload16(qkvb + (size_t)pos * QKV_LD + H_DIM + ksc * 8, &Klds[0][w * 512]);
  }
  ux8 vreg;
  #pragma unroll
  for (int j = 0; j < 8; j++) {
    int pos = chunk_lo + w * 8 + j;
    if (pos < 0) pos = 0;
    if (pos >= L_SEQ) pos = L_SEQ - 1;
    vreg[j] = qkvb[(size_t)pos * QKV_LD + 2 * H_DIM + d];
  }
  *(ux8*)&Vlds[0][vdst] = vreg;
  __syncthreads();   // K(0) drained; V(0) visible

  fx4 o[4] = {};
  u16* pb = Plds + w * 16 * P2_STR;
  const int prow = (w * 16 + c16) * P2_STR;

  for (int t = 0; t < 6; t++) {
    const int cur = t & 1, nxt = cur ^ 1;

    if (t < 5) {
      int pos = chunk_lo + (t + 1) * 64 + krow_s;
      if (pos < 0) pos = 0;
      if (pos >= L_SEQ) pos = L_SEQ - 1;
      gload16(qkvb + (size_t)pos * QKV_LD + H_DIM + ksc * 8, &Klds[nxt][w * 512]);
      #pragma unroll
      for (int j = 0; j < 8; j++) {
        int vp = chunk_lo + (t + 1) * 64 + w * 8 + j;
        if (vp < 0) vp = 0;
        if (vp >= L_SEQ) vp = L_SEQ - 1;
        vreg[j] = qkvb[(size_t)vp * QKV_LD + 2 * H_DIM + d];
      }
    }

    fx4 s[4];
    __builtin_amdgcn_s_setprio(1);
    #pragma unroll
    for (int kf = 0; kf < 4; kf++) {
      const int krow = kf * 16 + c16;                 // krow&7 == c16&7
      const bx8 b0 = *(const bx8*)&Klds[cur][krow * 64 + ((g ^ (c16 & 7)) << 3)];
      const bx8 b1 = *(const bx8*)&Klds[cur][krow * 64 + (((4 + g) ^ (c16 & 7)) << 3)];
      fx4 a = {};
      a = __builtin_amdgcn_mfma_f32_16x16x32_bf16(aq0, b0, a, 0, 0, 0);
      a = __builtin_amdgcn_mfma_f32_16x16x32_bf16(aq1, b1, a, 0, 0, 0);
      s[kf] = a;
    }
    __builtin_amdgcn_s_setprio(0);
    float pmax[4];
    #pragma unroll
    for (int r = 0; r < 4; r++) pmax[r] = -3.0e38f;
    #pragma unroll
    for (int kf = 0; kf < 4; kf++) {
      const int KF = t * 4 + kf;
      const int j = KF * 16 + c16;
      const bool kv = ((kvm >> KF) & 1u) != 0;
      #pragma unroll
      for (int r = 0; r < 4; r++) {
        const int c = cq + r;
        const bool keep = kv && (j >= c && j <= c + 256);
        const float val = keep ? s[kf][r] * 0.125f : -1.0e9f;
        s[kf][r] = val;
        pmax[r] = fmaxf(pmax[r], val);
      }
    }
    #pragma unroll
    for (int r = 0; r < 4; r++) {
      float mm = pmax[r];
      mm = fmaxf(mm, __shfl_xor(mm, 1));
      mm = fmaxf(mm, __shfl_xor(mm, 2));
      mm = fmaxf(mm, __shfl_xor(mm, 4));
      mm = fmaxf(mm, __shfl_xor(mm, 8));
      const float newm = fmaxf(m[r], mm);
      const float scale = __expf(m[r] - newm);
      m[r] = newm;
      l[r] *= scale;
      pgv[r] *= scale;
      #pragma unroll
      for (int df = 0; df < 4; df++) o[df][r] *= scale;
    }
    float lsum[4] = {0.f, 0.f, 0.f, 0.f};
    #pragma unroll
    for (int kf = 0; kf < 4; kf++)
      #pragma unroll
      for (int r = 0; r < 4; r++) {
        const float p = __expf(s[kf][r] - m[r]);
        s[kf][r] = p;
        lsum[r] += p;
      }
    #pragma unroll
    for (int r = 0; r < 4; r++) {
      float tt = lsum[r];
      tt += __shfl_xor(tt, 1);
      tt += __shfl_xor(tt, 2);
      tt += __shfl_xor(tt, 4);
      tt += __shfl_xor(tt, 8);
      l[r] += tt;
    }
    #pragma unroll
    for (int kf = 0; kf < 4; kf++) {
      #pragma unroll
      for (int r = 0; r < 4; r++) {
        const int rr = g * 4 + r;
        const int jj = kf * 16 + c16;       // 0..63 within tile
        pb[rr * P2_STR + (((jj >> 3) ^ (rr & 7)) << 3) + (jj & 7)] = f2bf(s[kf][r]);
      }
    }
    __builtin_amdgcn_s_setprio(1);
    #pragma unroll
    for (int kt = 0; kt < 2; kt++) {
      const int ckp = kt * 4 + g;           // chunk 0..7
      const bx8 pa = *(const bx8*)&Plds[prow + ((ckp ^ (c16 & 7)) << 3)];
      #pragma unroll
      for (int df = 0; df < 4; df++) {
        const int vrow = df * 16 + c16;
        const bx8 vvf = *(const bx8*)&Vlds[cur][vrow * 64 + ((ckp ^ (c16 & 7)) << 3)];
        o[df] = __builtin_amdgcn_mfma_f32_16x16x32_bf16(pa, vvf, o[df], 0, 0, 0);
      }
    }
    __builtin_amdgcn_s_setprio(0);
    if (t < 5) *(ux8*)&Vlds[nxt][vdst] = vreg;
    __syncthreads();
  }

  float rinv[4], pg[4];
  #pragma unroll
  for (int r = 0; r < 4; r++) {
    rinv[r] = 1.0f / l[r];
    pg[r] = __shfl(pgv[r], g * 16);
  }
  u16* ob = attnout + (size_t)b * L_SEQ * H_DIM + h * D_HEAD;
  const int posq = n * CHUNK + w * 16 + g * 4;
  #pragma unroll
  for (int df = 0; df < 4; df++) {
    const float v0f = bf2f(qkvb[2 * H_DIM + df * 16 + c16]);
    #pragma unroll
    for (int r = 0; r < 4; r++)
      ob[(size_t)(posq + r) * H_DIM + df * 16 + c16] =
          f2bf((o[df][r] + pg[r] * v0f) * rinv[r]);
  }
}

// =====================================================================
// Global row (query 0): split-flash kernel, 192 blocks (r17).
// =====================================================================
__global__ __launch_bounds__(512)
void attn_g_split(const u16* __restrict__ qkv, const int* __restrict__ amask,
                  float* __restrict__ gpm, float* __restrict__ gps,
                  float* __restrict__ gpo)
{
  __shared__ float qs[D_HEAD];
  __shared__ float es[512];
  __shared__ float red[8];
  const int tid = threadIdx.x;
  const int lane = tid & 63, w = tid >> 6;
  const int idx = blockIdx.x;
  const int bh = idx >> 3, seg = idx & 7;
  const int b = bh / N_HEADS, h = bh % N_HEADS;
  const u16* base = qkv + (size_t)b * L_SEQ * QKV_LD + h * D_HEAD;

  if (tid < D_HEAD) qs[tid] = bf2f(base[tid]);
  __syncthreads();

  const int key = seg * 512 + tid;
  const ux8* kp = (const ux8*)(base + (size_t)key * QKV_LD + H_DIM);
  float dot = 0.f;
  #pragma unroll
  for (int i = 0; i < 8; i++) {
    const ux8 kv = kp[i];
    #pragma unroll
    for (int j = 0; j < 8; j++) dot += qs[i * 8 + j] * bf2f(kv[j]);
  }
  float sv = dot * 0.125f;
  if (amask[b * L_SEQ + key] == 0) sv = -1.0e9f;

  float mv = sv;
  #pragma unroll
  for (int off = 32; off > 0; off >>= 1) mv = fmaxf(mv, __shfl_xor(mv, off));
  if (lane == 0) red[w] = mv;
  __syncthreads();
  float M = -3.0e38f;
  #pragma unroll
  for (int i = 0; i < 8; i++) M = fmaxf(M, red[i]);

  const float e = __expf(sv - M);
  es[tid] = e;
  float s = e;
  #pragma unroll
  for (int off = 32; off > 0; off >>= 1) s += __shfl_xor(s, off);
  __syncthreads();            // red reads (max) + es writes done
  if (lane == 0) red[w] = s;
  __syncthreads();
  float Sl = 0.f;
  #pragma unroll
  for (int i = 0; i < 8; i++) Sl += red[i];

  const int gi = tid >> 6, d = lane;
  const u16* vb = base + 2 * H_DIM + d;
  float acc = 0.f;
  #pragma unroll 4
  for (int i = 0; i < 64; i++) {
    const int kk = seg * 512 + gi * 64 + i;
    acc += es[gi * 64 + i] * bf2f(vb[(size_t)kk * QKV_LD]);
  }
  gpo[(((size_t)bh * NGSEG + seg) * 8 + gi) * D_HEAD + d] = acc;
  if (tid == 0) { gpm[bh * NGSEG + seg] = M; gps[bh * NGSEG + seg] = Sl; }
}

// combine split-flash partials -> query row 0
__global__ __launch_bounds__(64)
void attn_g_combine(const float* __restrict__ gpm, const float* __restrict__ gps,
                    const float* __restrict__ gpo, u16* __restrict__ attnout)
{
  const int bh = blockIdx.x;
  const int b = bh / N_HEADS, h = bh % N_HEADS;
  const int d = threadIdx.x;
  float M = -3.0e38f;
  #pragma unroll
  for (int s = 0; s < NGSEG; s++) M = fmaxf(M, gpm[bh * NGSEG + s]);
  float S = 0.f, acc = 0.f;
  #pragma unroll
  for (int s = 0; s < NGSEG; s++) {
    const float sc = __expf(gpm[bh * NGSEG + s] - M);
    S += gps[bh * NGSEG + s] * sc;
    #pragma unroll
    for (int gi = 0; gi < 8; gi++)
      acc += gpo[(((size_t)bh * NGSEG + s) * 8 + gi) * D_HEAD + d] * sc;
  }
  attnout[(size_t)b * L_SEQ * H_DIM + h * D_HEAD + d] = f2bf(acc / S);
}

// ---------------- LayerNorm kernels (bf16 residual, VECTORIZED G13) ----------------
__device__ __forceinline__ void block_stats(float sum, float sq, float* red,
                                            float& mean, float& rstd)
{
  const int lane = threadIdx.x & 63, wv = threadIdx.x >> 6;
  #pragma unroll
  for (int off = 32; off > 0; off >>= 1) {
    sum += __shfl_xor(sum, off);
    sq  += __shfl_xor(sq, off);
  }
  if (lane == 0) { red[wv] = sum; red[4 + wv] = sq; }
  __syncthreads();
  sum = red[0] + red[1] + red[2] + red[3];
  sq  = red[4] + red[5] + red[6] + red[7];
  mean = sum * (1.0f / H_DIM);
  const float var = sq * (1.0f / H_DIM) - mean * mean;
  rstd = rsqrtf(var + EPS_LN);
}

// embed+LN: threads 0..191 handle 4 cols each via float4/ux4 (row = 768)
__global__ __launch_bounds__(256)
void embed_ln_kernel(const int* __restrict__ ids, const float* __restrict__ wemb,
                     const float* __restrict__ pemb, const float* __restrict__ gam,
                     const float* __restrict__ bet, u16* __restrict__ xb)
{
  __shared__ float red[8];
  const int row = blockIdx.x, tid = threadIdx.x;
  const int l = row & (L_SEQ - 1);
  const int id = ids[row];
  float v[4];
  float sum = 0.f, sq = 0.f;
  const int c4 = tid * 4;
  if (tid < 192) {
    const fx4 wv = *(const fx4*)&wemb[(size_t)id * H_DIM + c4];
    const fx4 pv = *(const fx4*)&pemb[(size_t)l * H_DIM + c4];
    #pragma unroll
    for (int i = 0; i < 4; i++) {
      v[i] = wv[i] + pv[i];
      sum += v[i]; sq += v[i] * v[i];
    }
  }
  float mean, rstd;
  block_stats(sum, sq, red, mean, rstd);
  if (tid < 192) {
    const fx4 gv = *(const fx4*)&gam[c4];
    const fx4 bv = *(const fx4*)&bet[c4];
    ux4 out;
    #pragma unroll
    for (int i = 0; i < 4; i++)
      out[i] = f2bf((v[i] - mean) * rstd * gv[i] + bv[i]);
    *(ux4*)&xb[(size_t)row * H_DIM + c4] = out;
  }
}

// x_new = LN(x_old + y); vectorized ux4 loads/stores (threads 0..191)
__global__ __launch_bounds__(256)
void add_ln_kernel(u16* xio, const u16* __restrict__ yin,
                   const float* __restrict__ gam, const float* __restrict__ bet)
{
  __shared__ float red[8];
  const int row = blockIdx.x, tid = threadIdx.x;
  float v[4];
  float sum = 0.f, sq = 0.f;
  const int c4 = tid * 4;
  const size_t base = (size_t)row * H_DIM + c4;
  if (tid < 192) {
    const ux4 xv = *(const ux4*)&xio[base];
    const ux4 yv = *(const ux4*)&yin[base];
    #pragma unroll
    for (int i = 0; i < 4; i++) {
      v[i] = bf2f(xv[i]) + bf2f(yv[i]);
      sum += v[i]; sq += v[i] * v[i];
    }
  }
  float mean, rstd;
  block_stats(sum, sq, red, mean, rstd);
  if (tid < 192) {
    const fx4 gv = *(const fx4*)&gam[c4];
    const fx4 bv = *(const fx4*)&bet[c4];
    ux4 out;
    #pragma unroll
    for (int i = 0; i < 4; i++)
      out[i] = f2bf((v[i] - mean) * rstd * gv[i] + bv[i]);
    *(ux4*)&xio[base] = out;
  }
}

// ---------------- Fused weight prep ----------------
__global__ __launch_bounds__(256)
void prep_weights(const float* __restrict__ Wq, const float* __restrict__ Wk,
                  const float* __restrict__ Wv, const float* __restrict__ Wo,
                  const float* __restrict__ W1, const float* __restrict__ W2,
                  const float* __restrict__ Wfc,
                  const float* __restrict__ bq, const float* __restrict__ bk,
                  const float* __restrict__ bv,
                  u16* __restrict__ wqkvT, u16* __restrict__ woT,
                  u16* __restrict__ w1T, u16* __restrict__ w2T,
                  u16* __restrict__ wfcT, float* __restrict__ bqkv)
{
  const int t = blockIdx.x;
  const int tid = threadIdx.x;
  if (t >= 14112) {   // bias concat: 18 blocks
    const int idx = t - 14112;
    const int l = idx / 9, j = idx % 9;
    const int i = j * 256 + tid;
    if (i < H_DIM)          bqkv[l * QKV_LD + i] = bq[l * H_DIM + i];
    else if (i < 2 * H_DIM) bqkv[l * QKV_LD + i] = bk[l * H_DIM + i - H_DIM];
    else if (i < 3 * H_DIM) bqkv[l * QKV_LD + i] = bv[l * H_DIM + i - 2 * H_DIM];
    return;
  }
  const float* src; u16* dst; int K, N, r;
  if (t < 13824) {
    const int l = t / 6912; r = t % 6912;
    if (r < 2304) {
      const int m = r / 576; r = r % 576; K = H_DIM; N = H_DIM;
      if (m == 0)      src = Wq + (size_t)l * H_DIM * H_DIM;
      else if (m == 1) src = Wk + (size_t)l * H_DIM * H_DIM;
      else if (m == 2) src = Wv + (size_t)l * H_DIM * H_DIM;
      else             src = Wo + (size_t)l * H_DIM * H_DIM;
      dst = (m < 3) ? wqkvT + (size_t)l * QKV_LD * H_DIM + (size_t)m * H_DIM * H_DIM
                    : woT + (size_t)l * H_DIM * H_DIM;
    } else if (r < 4608) {
      r -= 2304; K = H_DIM; N = FF_DIM;
      src = W1 + (size_t)l * H_DIM * FF_DIM;
      dst = w1T + (size_t)l * FF_DIM * H_DIM;
    } else {
      r -= 4608; K = FF_DIM; N = H_DIM;
      src = W2 + (size_t)l * FF_DIM * H_DIM;
      dst = w2T + (size_t)l * H_DIM * FF_DIM;
    }
  } else {
    r = t - 13824; K = H_DIM; N = OUT_DIM; src = Wfc; dst = wfcT;
  }
  const int ntn = N >> 5;
  const int k0 = (r / ntn) * 32, n0 = (r % ntn) * 32;
  __shared__ float tile[32][33];
  const int tx = tid & 31, ty = tid >> 5;
  #pragma unroll
  for (int i = 0; i < 32; i += 8)
    tile[ty + i][tx] = src[(size_t)(k0 + ty + i) * N + n0 + tx];
  __syncthreads();
  #pragma unroll
  for (int i = 0; i < 32; i += 8)
    dst[(size_t)(n0 + ty + i) * K + k0 + tx] = f2bf(tile[tx][ty + i]);
}

// ---------------- host ----------------
extern "C" void kernel_launch(void* const* d_in, const int* in_sizes, int n_in,
                              void* d_out, int out_size, void* d_ws, size_t ws_size,
                              hipStream_t stream)
{
  (void)in_sizes; (void)n_in; (void)out_size; (void)ws_size;
  const int*   ids   = (const int*)d_in[0];
  const int*   amask = (const int*)d_in[1];
  const float* wemb  = (const float*)d_in[2];
  const float* pemb  = (const float*)d_in[3];
  const float* elns  = (const float*)d_in[4];
  const float* elnb  = (const float*)d_in[5];
  const float* Wq    = (const float*)d_in[6];
  const float* bq    = (const float*)d_in[7];
  const float* Wk    = (const float*)d_in[8];
  const float* bk    = (const float*)d_in[9];
  const float* Wv    = (const float*)d_in[10];
  const float* bv    = (const float*)d_in[11];
  const float* Wo    = (const float*)d_in[12];
  const float* bo    = (const float*)d_in[13];
  const float* ln1s  = (const float*)d_in[14];
  const float* ln1b  = (const float*)d_in[15];
  const float* W1    = (const float*)d_in[16];
  const float* b1    = (const float*)d_in[17];
  const float* W2    = (const float*)d_in[18];
  const float* b2    = (const float*)d_in[19];
  const float* ln2s  = (const float*)d_in[20];
  const float* ln2b  = (const float*)d_in[21];
  const float* Wfc   = (const float*)d_in[22];
  const float* bfc   = (const float*)d_in[23];

  char* ws = (char*)d_ws;
  size_t off = 0;
  auto alloc = [&](size_t bytes) -> void* {
    void* p = ws + off;
    off += (bytes + 255) & ~(size_t)255;
    return p;
  };
  u16* xb     = (u16*)alloc((size_t)M_ROWS * H_DIM * 2);   // residual stream (post-LN)
  u16* projb  = (u16*)alloc((size_t)M_ROWS * H_DIM * 2);
  u16* big    = (u16*)alloc((size_t)M_ROWS * FF_DIM * 2);  // qkv / ff1 time-share
  u16* attno  = (u16*)alloc((size_t)M_ROWS * H_DIM * 2);
  u16* wqkvT  = (u16*)alloc((size_t)2 * QKV_LD * H_DIM * 2);
  u16* woT    = (u16*)alloc((size_t)2 * H_DIM * H_DIM * 2);
  u16* w1T    = (u16*)alloc((size_t)2 * FF_DIM * H_DIM * 2);
  u16* w2T    = (u16*)alloc((size_t)2 * H_DIM * FF_DIM * 2);
  u16* wfcT   = (u16*)alloc((size_t)OUT_DIM * H_DIM * 2);
  float* bqkv = (float*)alloc(2 * QKV_LD * 4);
  float* gpm  = (float*)alloc((size_t)BATCH * N_HEADS * NGSEG * 4);
  float* gps  = (float*)alloc((size_t)BATCH * N_HEADS * NGSEG * 4);
  float* gpo  = (float*)alloc((size_t)BATCH * N_HEADS * NGSEG * 8 * D_HEAD * 4);

  u16* qkvb = big;
  u16* ff1  = big;

  prep_weights<<<14130, 256, 0, stream>>>(Wq, Wk, Wv, Wo, W1, W2, Wfc,
                                          bq, bk, bv,
                                          wqkvT, woT, w1T, w2T, wfcT, bqkv);
  embed_ln_kernel<<<M_ROWS, 256, 0, stream>>>(ids, wemb, pemb, elns, elnb, xb);

  for (int l = 0; l < 2; l++) {
    gemm_s<1, 0, 0><<<(M_ROWS / 128) * (QKV_LD / 128), 256, 0, stream>>>(
        xb, wqkvT + (size_t)l * QKV_LD * H_DIM, bqkv + l * QKV_LD,
        nullptr, qkvb, nullptr, QKV_LD, H_DIM);
    attn_local_kernel<<<BATCH * N_HEADS * N_CHUNK, 512, 0, stream>>>(qkvb, amask, attno);
    attn_g_split<<<BATCH * N_HEADS * NGSEG, 512, 0, stream>>>(qkvb, amask, gpm, gps, gpo);
    attn_g_combine<<<BATCH * N_HEADS, 64, 0, stream>>>(gpm, gps, gpo, attno);
    gemm_s<1, 0, 0><<<(M_ROWS / 128) * (H_DIM / 128), 256, 0, stream>>>(
        attno, woT + (size_t)l * H_DIM * H_DIM, bo + l * H_DIM,
        nullptr, projb, nullptr, H_DIM, H_DIM);
    add_ln_kernel<<<M_ROWS, 256, 0, stream>>>(xb, projb, ln1s + l * H_DIM, ln1b + l * H_DIM);
    gemm_s<1, 1, 0><<<(M_ROWS / 128) * (FF_DIM / 128), 256, 0, stream>>>(
        xb, w1T + (size_t)l * FF_DIM * H_DIM, b1 + l * FF_DIM,
        nullptr, ff1, nullptr, FF_DIM, H_DIM);
    gemm_s<1, 0, 0><<<(M_ROWS / 128) * (H_DIM / 128), 256, 0, stream>>>(
        ff1, w2T + (size_t)l * H_DIM * FF_DIM, b2 + l * H_DIM,
        nullptr, projb, nullptr, H_DIM, FF_DIM);
    add_ln_kernel<<<M_ROWS, 256, 0, stream>>>(xb, projb, ln2s + l * H_DIM, ln2b + l * H_DIM);
  }

  float* vdn = (float*)d_out;
  float* cls = vdn + (size_t)BATCH * L_SEQ * OUT_DIM;
  gemm_s<0, 0, 1><<<(M_ROWS / 128) * (OUT_DIM / 128), 256, 0, stream>>>(
      xb, wfcT, bfc, vdn, nullptr, cls, OUT_DIM, H_DIM);
}